// Round 21
// baseline (2645.138 us; speedup 1.0000x reference)
//
#include <hip/hip_runtime.h>
#include <hip/hip_bf16.h>
#include <math.h>

#define NN 8192
#define CC 256
#define KK 16
#define K17 17
#define KE 20           // extracted+stored per row
#define EI 8            // j-eighths in screening
#define NCH 24          // candidates kept per eighth
#define NC (EI * NCH)   // 192 candidates per row
#define NF 3            // layer-1 fork rows
#define CAP 2048        // max affected rows per fork
#define TAUF 1e-2
#define TAU_L2 4e-3
#define DGATE 0.21f
#define LLEN 8

typedef unsigned long long ull;
typedef unsigned short ushort_t;
typedef short bf16x8 __attribute__((ext_vector_type(8)));
typedef float f32x4 __attribute__((ext_vector_type(4)));

__device__ inline double shfl_xor_d(double x, int m) {
  union { double d; int i[2]; } u;
  u.d = x;
  u.i[0] = __shfl_xor(u.i[0], m);
  u.i[1] = __shfl_xor(u.i[1], m);
  return u.d;
}

// ---------------- x0 prep: promote + bf16 + fp32 row-sq (screening-only) ----------------
__global__ void xprep_kernel(const float* __restrict__ x, double* __restrict__ xd,
                             ushort_t* __restrict__ xb, float* __restrict__ sq) {
  __shared__ float red[256];
  const int i = blockIdx.x;
  const int tid = threadIdx.x;
  const float v = x[(size_t)i * CC + tid];
  xd[(size_t)i * CC + tid] = (double)v;
  __hip_bfloat16 hb = __float2bfloat16(v);
  xb[(size_t)i * CC + tid] = *(ushort_t*)&hb;
  red[tid] = v * v;
  __syncthreads();
  for (int s = 128; s > 0; s >>= 1) {
    if (tid < s) red[tid] += red[tid + s];
    __syncthreads();
  }
  if (tid == 0) sq[i] = red[0];
}

// ---------------- h = xd @ W : full fp64 ----------------
__global__ void hgemm64_kernel(const double* __restrict__ xd, const float* __restrict__ W,
                               double* __restrict__ h) {
  __shared__ double xs[16][CC];
  const int tid = threadIdx.x;
  const int n0 = blockIdx.x * 16;
#pragma unroll
  for (int r = 0; r < 16; ++r) xs[r][tid] = xd[(size_t)(n0 + r) * CC + tid];
  __syncthreads();
  double acc[16];
#pragma unroll
  for (int n = 0; n < 16; ++n) acc[n] = 0.0;
  const float* wp = W + tid;
  for (int k = 0; k < CC; ++k) {
    const double w = (double)wp[(size_t)k * CC];
#pragma unroll
    for (int n = 0; n < 16; ++n) acc[n] += xs[n][k] * w;
  }
#pragma unroll
  for (int n = 0; n < 16; ++n) h[(size_t)(n0 + n) * CC + tid] = acc[n];
}

// ---------------- alpha dots, fp64, one wave per row ----------------
__global__ void alpha64_kernel(const double* __restrict__ h, const float* __restrict__ a_s,
                               const float* __restrict__ a_d, double* __restrict__ als,
                               double* __restrict__ ald) {
  int row = blockIdx.x * 4 + (threadIdx.x >> 6);
  int lane = threadIdx.x & 63;
  const double* hp = h + (size_t)row * CC + 4 * lane;
  double s = 0.0, t = 0.0;
#pragma unroll
  for (int q = 0; q < 4; ++q) {
    const double hv = hp[q];
    s += hv * (double)a_s[4 * lane + q];
    t += hv * (double)a_d[4 * lane + q];
  }
#pragma unroll
  for (int d = 1; d < 64; d <<= 1) {
    s += shfl_xor_d(s, d);
    t += shfl_xor_d(t, d);
  }
  if (lane == 0) { als[row] = s; ald[row] = t; }
}

// ---------------- bf16 MFMA screening v5: 1-wave blocks, j-eighths ----------------
// grid = (NN/16)*EI. Block = 1 wave; tile = b>>3, eighth = b&7.
__launch_bounds__(64, 1)
__global__ void screen_bf16(const ushort_t* __restrict__ xb, const float* __restrict__ sq,
                            int* __restrict__ cand) {
  const int lane = threadIdx.x;
  const int g4   = lane >> 4;
  const int l16  = lane & 15;
  const int tile = blockIdx.x >> 3;
  const int eighth = blockIdx.x & 7;
  const int i0   = tile * 16;

  bf16x8 af[8];
  {
    const ushort_t* ap = xb + (size_t)(i0 + l16) * CC + 8 * g4;
#pragma unroll
    for (int ks = 0; ks < 8; ++ks) af[ks] = *(const bf16x8*)(ap + ks * 32);
  }
  float sqi[4];
#pragma unroll
  for (int r = 0; r < 4; ++r) sqi[r] = sq[i0 + 4 * g4 + r];

  float ld[4][LLEN]; int lj[4][LLEN];
#pragma unroll
  for (int r = 0; r < 4; ++r)
#pragma unroll
    for (int s = 0; s < LLEN; ++s) { ld[r][s] = INFINITY; lj[r][s] = 0x7fffffff; }

  const int jbeg = eighth * (NN / EI);
#pragma unroll 1
  for (int t = 0; t < (NN / EI) / 64; ++t) {
    const int j0 = jbeg + t * 64;
#pragma unroll
    for (int jt = 0; jt < 4; ++jt) {
      f32x4 acc = {0.f, 0.f, 0.f, 0.f};
      const ushort_t* bp = xb + (size_t)(j0 + jt * 16 + l16) * CC + 8 * g4;
#pragma unroll
      for (int ks = 0; ks < 8; ++ks) {
        const bf16x8 bv = *(const bf16x8*)(bp + ks * 32);
        acc = __builtin_amdgcn_mfma_f32_16x16x32_bf16(af[ks], bv, acc, 0, 0, 0);
      }
      const int jc = j0 + jt * 16 + l16;
      const float sqj = sq[jc];
#pragma unroll
      for (int r = 0; r < 4; ++r) {
        const float dv = (sqi[r] + sqj) - 2.f * acc[r];
        const bool self = (jc == i0 + 4 * g4 + r);
        if (!self && (dv < ld[r][LLEN - 1] ||
                      (dv == ld[r][LLEN - 1] && jc < lj[r][LLEN - 1]))) {
          ld[r][LLEN - 1] = dv; lj[r][LLEN - 1] = jc;
#pragma unroll
          for (int s = LLEN - 1; s > 0; --s) {
            const bool sw = (ld[r][s] < ld[r][s - 1]) ||
                            (ld[r][s] == ld[r][s - 1] && lj[r][s] < lj[r][s - 1]);
            const float tv = ld[r][s - 1]; const int jv = lj[r][s - 1];
            ld[r][s - 1] = sw ? ld[r][s] : ld[r][s - 1];
            lj[r][s - 1] = sw ? lj[r][s] : lj[r][s - 1];
            ld[r][s] = sw ? tv : ld[r][s];
            lj[r][s] = sw ? jv : lj[r][s];
          }
        }
      }
    }
  }

#pragma unroll
  for (int r = 0; r < 4; ++r) {
    const int rr = 4 * g4 + r;
#pragma unroll 1
    for (int s = 0; s < NCH; ++s) {
      float hd = ld[r][0]; int hj = lj[r][0];
#pragma unroll
      for (int dlt = 1; dlt < 16; dlt <<= 1) {
        const float od = __shfl_xor(hd, dlt);
        const int oj = __shfl_xor(hj, dlt);
        if (od < hd || (od == hd && oj < hj)) { hd = od; hj = oj; }
      }
      if (ld[r][0] == hd && lj[r][0] == hj) {
#pragma unroll
        for (int s2 = 0; s2 < LLEN - 1; ++s2) {
          ld[r][s2] = ld[r][s2 + 1]; lj[r][s2] = lj[r][s2 + 1];
        }
        ld[r][LLEN - 1] = INFINITY; lj[r][LLEN - 1] = 0x7fffffff;
      }
      if (l16 == 0) cand[(size_t)(i0 + rr) * NC + eighth * NCH + s] = hj;
    }
  }
}

// ---------------- fp64 exact refine of 192 candidates -> sorted top-20 + gap ----------------
__launch_bounds__(256, 1)
__global__ void refine192(const double* __restrict__ xd, const int* __restrict__ cand,
                          int* __restrict__ kj, double* __restrict__ kd,
                          double* __restrict__ gapd) {
  __shared__ double rd[NC];
  __shared__ int    rj[NC];
  const int row = blockIdx.x;
  const int tid = threadIdx.x;
  if (tid < NC) {
    const int j = cand[(size_t)row * NC + tid];
    const double* xi = xd + (size_t)row * CC;
    const double* xj = xd + (size_t)j * CC;
    double acc = 0.0;
#pragma unroll 4
    for (int k = 0; k < CC; ++k) {
      const double d = xi[k] - xj[k];
      acc = fma(d, d, acc);
    }
    rd[tid] = acc;
    rj[tid] = j;
  }
  __syncthreads();
  if (tid < 64) {
    volatile double* vd = rd;
    volatile int*    vj = rj;
    double d16 = 0.0, d17 = 0.0;
    for (int s = 0; s < KE; ++s) {
      double bv = 1e300; int bj = 0x7fffffff; int bp = -1;
      for (int e = tid; e < NC; e += 64) {
        const double v = vd[e];
        const int jv = vj[e];
        if (v < bv || (v == bv && jv < bj)) { bv = v; bj = jv; bp = e; }
      }
#pragma unroll
      for (int dlt = 1; dlt < 64; dlt <<= 1) {
        const double ov = shfl_xor_d(bv, dlt);
        const int oj = __shfl_xor(bj, dlt);
        const int op = __shfl_xor(bp, dlt);
        if (ov < bv || (ov == bv && oj < bj)) { bv = ov; bj = oj; bp = op; }
      }
      if (tid == 0) {
        kj[(size_t)row * KE + s] = bj;
        kd[(size_t)row * KE + s] = bv;
        vd[bp] = 1e300;
        vj[bp] = 0x7fffffff;
      }
      if (s == KK - 1) d16 = bv;
      if (s == KK)     d17 = bv;
    }
    if (tid == 0) gapd[row] = d17 - d16;
  }
}

// ---------------- dual-branch softmax+aggregate + gated blend (+aux epilogue) ----------------
__global__ void agg_blend(const double* __restrict__ xin, const double* __restrict__ h,
                          const int* __restrict__ knn, int ldk, const double* __restrict__ gapd,
                          const double* __restrict__ als, const double* __restrict__ ald,
                          const float* __restrict__ bias, double tau,
                          double* __restrict__ xd_out, ushort_t* __restrict__ xb_out,
                          float* __restrict__ sq_out, int do_aux) {
  const int i = blockIdx.x;
  const int tid = threadIdx.x;
  __shared__ int idx[K17 + 1];
  __shared__ double attA[K17 + 1];
  __shared__ double attB[K17 + 1];
  __shared__ float red[256];
  if (tid < K17) idx[tid] = knn[(size_t)i * ldk + tid];
  if (tid == K17) idx[K17] = i;
  __syncthreads();
  if (tid == 0) {
    double e[K17 + 1];
#pragma unroll
    for (int l = 0; l < K17 + 1; ++l) {
      const double t = als[idx[l]] + ald[i];
      e[l] = (t >= 0.0) ? t : 0.2 * t;
    }
    {  // branch A: {0..15} + self
      double mx = e[K17];
#pragma unroll
      for (int l = 0; l < KK; ++l) mx = fmax(mx, e[l]);
      double den = 0.0, p[K17 + 1];
#pragma unroll
      for (int l = 0; l < KK; ++l) { p[l] = exp(e[l] - mx); den += p[l]; }
      p[K17] = exp(e[K17] - mx); den += p[K17];
      const double inv = 1.0 / den;
#pragma unroll
      for (int l = 0; l < K17 + 1; ++l) attA[l] = 0.0;
#pragma unroll
      for (int l = 0; l < KK; ++l) attA[l] = p[l] * inv;
      attA[K17] = p[K17] * inv;
    }
    {  // branch B: {0..14, 16} + self
      double mx = e[K17];
#pragma unroll
      for (int l = 0; l < KK - 1; ++l) mx = fmax(mx, e[l]);
      mx = fmax(mx, e[KK]);
      double den = 0.0, p[K17 + 1];
#pragma unroll
      for (int l = 0; l < KK - 1; ++l) { p[l] = exp(e[l] - mx); den += p[l]; }
      p[KK] = exp(e[KK] - mx); den += p[KK];
      p[K17] = exp(e[K17] - mx); den += p[K17];
      const double inv = 1.0 / den;
#pragma unroll
      for (int l = 0; l < K17 + 1; ++l) attB[l] = 0.0;
#pragma unroll
      for (int l = 0; l < KK - 1; ++l) attB[l] = p[l] * inv;
      attB[KK] = p[KK] * inv;
      attB[K17] = p[K17] * inv;
    }
  }
  __syncthreads();
  double outA = 0.0, outB = 0.0;
#pragma unroll 1
  for (int l = 0; l < K17 + 1; ++l) {
    const double hv = h[(size_t)idx[l] * CC + tid];
    outA += attA[l] * hv;
    outB += attB[l] * hv;
  }
  const double xv = xin[(size_t)i * CC + tid];
  const double bb = (double)bias[tid];
  const double rA = xv + fmax(outA + bb, 0.0);
  const double rB = xv + fmax(outB + bb, 0.0);
  red[tid] = (float)fabs(rA - rB);
  __syncthreads();
  for (int s = 128; s > 0; s >>= 1) {
    if (tid < s) red[tid] = fmaxf(red[tid], red[tid + s]);
    __syncthreads();
  }
  const bool blend = (gapd[i] < tau) && (red[0] <= DGATE);
  const double res = blend ? 0.5 * (rA + rB) : rA;
  xd_out[(size_t)i * CC + tid] = res;
  if (do_aux) {   // produce bf16 + fp32 row-sq for next layer's screening
    const float x32 = (float)res;
    __hip_bfloat16 hb = __float2bfloat16(x32);
    xb_out[(size_t)i * CC + tid] = *(ushort_t*)&hb;
    __syncthreads();
    red[tid] = x32 * x32;
    __syncthreads();
    for (int s = 128; s > 0; s >>= 1) {
      if (tid < s) red[tid] += red[tid + s];
      __syncthreads();
    }
    if (tid == 0) sq_out[i] = red[0];
  }
}

// ---------------- pick NF smallest layer-1 gaps (< TAUF) ----------------
__global__ void select_forks(const double* __restrict__ gapd, int* __restrict__ forks) {
  const int lane = threadIdx.x;
  int ch0 = -2, ch1 = -2;
  for (int f = 0; f < NF; ++f) {
    double bv = TAUF; int bi = 0x7fffffff;
    for (int i = lane; i < NN; i += 64) {
      if (i == ch0 || i == ch1) continue;
      const double v = gapd[i];
      if (v < bv || (v == bv && i < bi)) { bv = v; bi = i; }
    }
#pragma unroll
    for (int d = 1; d < 64; d <<= 1) {
      const double ov = shfl_xor_d(bv, d);
      const int oi = __shfl_xor(bi, d);
      if (ov < bv || (ov == bv && oi < bi)) { bv = ov; bi = oi; }
    }
    const int win = (bi == 0x7fffffff) ? -1 : bi;
    if (lane == 0) forks[f] = win;
    if (f == 0) ch0 = win;
    if (f == 1) ch1 = win;
  }
}

// ---------------- branch-B layer-1 output row per fork ----------------
__global__ void fork_rowB(const double* __restrict__ xin, const double* __restrict__ h,
                          const int* __restrict__ knn, const double* __restrict__ als,
                          const double* __restrict__ ald, const float* __restrict__ bias,
                          const int* __restrict__ forks, double* __restrict__ rowB) {
  const int f = blockIdx.x;
  const int tid = threadIdx.x;
  const int i = forks[f];
  if (i < 0) { rowB[(size_t)f * CC + tid] = 0.0; return; }
  __shared__ int idx[K17 + 1];
  __shared__ double attB[K17 + 1];
  if (tid < K17) idx[tid] = knn[(size_t)i * KE + tid];
  if (tid == K17) idx[K17] = i;
  __syncthreads();
  if (tid == 0) {
    double e[K17 + 1];
#pragma unroll
    for (int l = 0; l < K17 + 1; ++l) {
      const double t = als[idx[l]] + ald[i];
      e[l] = (t >= 0.0) ? t : 0.2 * t;
    }
    double mx = e[K17];
#pragma unroll
    for (int l = 0; l < KK - 1; ++l) mx = fmax(mx, e[l]);
    mx = fmax(mx, e[KK]);
    double den = 0.0, p[K17 + 1];
#pragma unroll
    for (int l = 0; l < KK - 1; ++l) { p[l] = exp(e[l] - mx); den += p[l]; }
    p[KK] = exp(e[KK] - mx); den += p[KK];
    p[K17] = exp(e[K17] - mx); den += p[K17];
    const double inv = 1.0 / den;
#pragma unroll
    for (int l = 0; l < K17 + 1; ++l) attB[l] = 0.0;
#pragma unroll
    for (int l = 0; l < KK - 1; ++l) attB[l] = p[l] * inv;
    attB[KK] = p[KK] * inv;
    attB[K17] = p[K17] * inv;
  }
  __syncthreads();
  double outB = 0.0;
#pragma unroll 1
  for (int l = 0; l < K17 + 1; ++l)
    outB += attB[l] * h[(size_t)idx[l] * CC + tid];
  rowB[(size_t)f * CC + tid] =
      xin[(size_t)i * CC + tid] + fmax(outB + (double)bias[tid], 0.0);
}

// ---------------- f-folded: hm = rowB @ W2 + als_m/ald_m ----------------
__global__ void fork_hm_alpha(const double* __restrict__ rowB, const float* __restrict__ W2,
                              const float* __restrict__ a_s2, const float* __restrict__ a_d2,
                              const int* __restrict__ forks,
                              double* __restrict__ hm3, double* __restrict__ alsm3,
                              double* __restrict__ aldm3) {
  const int f = blockIdx.x;
  const int m = forks[f];
  if (m < 0) return;
  __shared__ double rb[CC];
  __shared__ double hs[CC];
  const int tid = threadIdx.x;
  rb[tid] = rowB[(size_t)f * CC + tid];
  __syncthreads();
  double acc = 0.0;
  const float* wp = W2 + tid;
  for (int k = 0; k < CC; ++k) {
    const double w = (double)wp[(size_t)k * CC];
    acc += rb[k] * w;
  }
  hm3[(size_t)f * CC + tid] = acc;
  hs[tid] = acc;
  __syncthreads();
  if (tid < 64) {
    const double* hp = hs + 4 * tid;
    double s = 0.0, t = 0.0;
#pragma unroll
    for (int q = 0; q < 4; ++q) {
      const double hv = hp[q];
      s += hv * (double)a_s2[4 * tid + q];
      t += hv * (double)a_d2[4 * tid + q];
    }
#pragma unroll
    for (int d = 1; d < 64; d <<= 1) {
      s += shfl_xor_d(s, d);
      t += shfl_xor_d(t, d);
    }
    if (tid == 0) { alsm3[f] = s; aldm3[f] = t; }
  }
}

// ---------------- f-folded: dmB3[f][i] = ||x1A_i - rowB_f||^2 ----------------
__global__ void fork_dm(const double* __restrict__ x1A, const double* __restrict__ rowB,
                        const int* __restrict__ forks, double* __restrict__ dmB3) {
  const int f = blockIdx.x / (NN / 256);
  const int ib = blockIdx.x % (NN / 256);
  const int m = forks[f];
  if (m < 0) return;
  __shared__ double rb[CC];
  const int tid = threadIdx.x;
  rb[tid] = rowB[(size_t)f * CC + tid];
  __syncthreads();
  const int i = ib * 256 + tid;
  const double* xi = x1A + (size_t)i * CC;
  double acc = 0.0;
#pragma unroll 4
  for (int k = 0; k < CC; ++k) {
    const double t = xi[k] - rb[k];
    acc = fma(t, t, acc);
  }
  dmB3[(size_t)f * NN + i] = acc;
}

// ---------------- f-folded: incremental top-17, affected rows only ----------------
__global__ void fork_update_knn(const int* __restrict__ kj, const double* __restrict__ kd,
                                const double* __restrict__ dmB3, const int* __restrict__ forks,
                                int* __restrict__ kbj3, double* __restrict__ gapdB3,
                                int* __restrict__ afflist, int* __restrict__ affcnt) {
  const int f = blockIdx.x / (NN / 4);
  const int rb = blockIdx.x % (NN / 4);
  const int m = forks[f];
  if (m < 0) return;
  const int row = rb * 4 + (threadIdx.x >> 6);
  const int lane = threadIdx.x & 63;
  if (row == m) return;
  double d = 1e300;
  int j = 0x7fffffff;
  if (lane < KE) { j = kj[(size_t)row * KE + lane]; d = kd[(size_t)row * KE + lane]; }
  const ull pres = __ballot(lane < KE && j == m);
  const double dm = dmB3[(size_t)f * NN + row];
  const double k17d = kd[(size_t)row * KE + K17 - 1];
  const int    k17j = kj[(size_t)row * KE + K17 - 1];
  const bool ins = (dm < k17d) || (dm == k17d && m < k17j);
  if (pres == 0ull && !ins) return;          // unaffected: fB == fA bit-identical
  if (lane < KE && j == m) d = dm;
  if (lane == KE && pres == 0ull) { j = m; d = dm; }
  double d16 = 0.0, d17 = 0.0;
#pragma unroll 1
  for (int s = 0; s < K17; ++s) {
    double v = d; int e = j;
#pragma unroll
    for (int dlt = 1; dlt < 64; dlt <<= 1) {
      const double ov = shfl_xor_d(v, dlt);
      const int oe = __shfl_xor(e, dlt);
      if (ov < v || (ov == v && oe < e)) { v = ov; e = oe; }
    }
    if (j == e) d = 1e300;
    if (lane == 0) kbj3[((size_t)f * NN + row) * K17 + s] = e;
    if (s == KK - 1) d16 = v;
    if (s == KK)     d17 = v;
  }
  if (lane == 0) {
    gapdB3[(size_t)f * NN + row] = d17 - d16;
    const int slot = atomicAdd(&affcnt[f], 1);
    if (slot < CAP) afflist[(size_t)f * CAP + slot] = row;
  }
}

// ---------------- f-folded: row m's own top-17 over dmB ----------------
__launch_bounds__(256, 1)
__global__ void fork_row_m_knn(const double* __restrict__ dmB3, const int* __restrict__ forks,
                               int* __restrict__ kbj3, double* __restrict__ gapdB3,
                               int* __restrict__ afflist, int* __restrict__ affcnt) {
  const int f = blockIdx.x;
  const int m = forks[f];
  if (m < 0) return;
  __shared__ double md[256 * 18];
  __shared__ int    mj[256 * 18];
  const int tid = threadIdx.x;
  double td[18]; int tj[18];
#pragma unroll
  for (int s = 0; s < 18; ++s) { td[s] = 1e300; tj[s] = 0x7fffffff; }
  for (int j = tid; j < NN; j += 256) {
    if (j == m) continue;
    const double d = dmB3[(size_t)f * NN + j];
    if (d < td[17] || (d == td[17] && j < tj[17])) {
      td[17] = d; tj[17] = j;
#pragma unroll
      for (int s = 17; s > 0; --s) {
        const bool sw = (td[s] < td[s - 1]) ||
                        (td[s] == td[s - 1] && tj[s] < tj[s - 1]);
        const double tv = td[s - 1]; const int jv = tj[s - 1];
        td[s - 1] = sw ? td[s] : td[s - 1];
        tj[s - 1] = sw ? tj[s] : tj[s - 1];
        td[s] = sw ? tv : td[s];
        tj[s] = sw ? jv : tj[s];
      }
    }
  }
#pragma unroll
  for (int s = 0; s < 18; ++s) { md[tid * 18 + s] = td[s]; mj[tid * 18 + s] = tj[s]; }
  __syncthreads();
  if (tid < 64) {
    volatile double* vmd = md;
    volatile int*    vmj = mj;
    double d16 = 0.0, d17 = 0.0;
    for (int r = 0; r < K17; ++r) {
      double bv = 1e300; int bj = 0x7fffffff; int bp = -1;
      for (int e = tid; e < 256 * 18; e += 64) {
        const double v = vmd[e];
        const int jv = vmj[e];
        if (v < bv || (v == bv && jv < bj)) { bv = v; bj = jv; bp = e; }
      }
#pragma unroll
      for (int dlt = 1; dlt < 64; dlt <<= 1) {
        const double ov = shfl_xor_d(bv, dlt);
        const int oj = __shfl_xor(bj, dlt);
        const int op = __shfl_xor(bp, dlt);
        if (ov < bv || (ov == bv && oj < bj)) { bv = ov; bj = oj; bp = op; }
      }
      if (tid == 0) {
        kbj3[((size_t)f * NN + m) * K17 + r] = bj;
        vmd[bp] = 1e300;
        vmj[bp] = 0x7fffffff;
      }
      if (r == KK - 1) d16 = bv;
      if (r == KK)     d17 = bv;
    }
    if (tid == 0) {
      gapdB3[(size_t)f * NN + m] = d17 - d16;
      const int slot = atomicAdd(&affcnt[f], 1);
      if (slot < CAP) afflist[(size_t)f * CAP + slot] = m;
    }
  }
}

// ---------------- f-folded: agg over affected rows -> compact fnBc + maxd ----------------
__global__ void fork_agg_aff(const double* __restrict__ x1A, const double* __restrict__ h,
                             const int* __restrict__ kbj3, const double* __restrict__ gapdB3,
                             const double* __restrict__ als, const double* __restrict__ ald,
                             const double* __restrict__ alsm3, const double* __restrict__ aldm3,
                             const double* __restrict__ hm3, const double* __restrict__ rowB,
                             const float* __restrict__ bias, const int* __restrict__ forks,
                             const int* __restrict__ afflist, const int* __restrict__ affcnt,
                             const double* __restrict__ fnA, double* __restrict__ fnBc,
                             unsigned* __restrict__ maxd) {
  const int f = blockIdx.x >> 7;          // 128 blocks per fork
  const int qb = blockIdx.x & 127;
  const int m = forks[f];
  if (m < 0) return;
  const int cnt = min(affcnt[f], CAP);
  const int tid = threadIdx.x;
  __shared__ int idx[K17 + 1];
  __shared__ double attA[K17 + 1];
  __shared__ double attB[K17 + 1];
  __shared__ float red[256];
#pragma unroll 1
  for (int q = qb; q < cnt; q += 128) {
    const int i = afflist[(size_t)f * CAP + q];
    if (tid < K17) idx[tid] = kbj3[((size_t)f * NN + i) * K17 + tid];
    if (tid == K17) idx[K17] = i;
    __syncthreads();
    if (tid == 0) {
      const double aldi = (i == m) ? aldm3[f] : ald[i];
      double e[K17 + 1];
#pragma unroll
      for (int l = 0; l < K17 + 1; ++l) {
        const int ix = idx[l];
        const double a = (ix == m) ? alsm3[f] : als[ix];
        const double t = a + aldi;
        e[l] = (t >= 0.0) ? t : 0.2 * t;
      }
      {
        double mx = e[K17];
#pragma unroll
        for (int l = 0; l < KK; ++l) mx = fmax(mx, e[l]);
        double den = 0.0, p[K17 + 1];
#pragma unroll
        for (int l = 0; l < KK; ++l) { p[l] = exp(e[l] - mx); den += p[l]; }
        p[K17] = exp(e[K17] - mx); den += p[K17];
        const double inv = 1.0 / den;
#pragma unroll
        for (int l = 0; l < K17 + 1; ++l) attA[l] = 0.0;
#pragma unroll
        for (int l = 0; l < KK; ++l) attA[l] = p[l] * inv;
        attA[K17] = p[K17] * inv;
      }
      {
        double mx = e[K17];
#pragma unroll
        for (int l = 0; l < KK - 1; ++l) mx = fmax(mx, e[l]);
        mx = fmax(mx, e[KK]);
        double den = 0.0, p[K17 + 1];
#pragma unroll
        for (int l = 0; l < KK - 1; ++l) { p[l] = exp(e[l] - mx); den += p[l]; }
        p[KK] = exp(e[KK] - mx); den += p[KK];
        p[K17] = exp(e[K17] - mx); den += p[K17];
        const double inv = 1.0 / den;
#pragma unroll
        for (int l = 0; l < K17 + 1; ++l) attB[l] = 0.0;
#pragma unroll
        for (int l = 0; l < KK - 1; ++l) attB[l] = p[l] * inv;
        attB[KK] = p[KK] * inv;
        attB[K17] = p[K17] * inv;
      }
    }
    __syncthreads();
    double outA = 0.0, outB = 0.0;
#pragma unroll 1
    for (int l = 0; l < K17 + 1; ++l) {
      const int ix = idx[l];
      const double hv = (ix == m) ? hm3[(size_t)f * CC + tid] : h[(size_t)ix * CC + tid];
      outA += attA[l] * hv;
      outB += attB[l] * hv;
    }
    const double xv = (i == m) ? rowB[(size_t)f * CC + tid] : x1A[(size_t)i * CC + tid];
    const double bb = (double)bias[tid];
    const double rA = xv + fmax(outA + bb, 0.0);
    const double rB = xv + fmax(outB + bb, 0.0);
    red[tid] = (float)fabs(rA - rB);
    __syncthreads();
    for (int s = 128; s > 0; s >>= 1) {
      if (tid < s) red[tid] = fmaxf(red[tid], red[tid + s]);
      __syncthreads();
    }
    const bool blend = (gapdB3[(size_t)f * NN + i] < TAU_L2) && (red[0] <= DGATE);
    const double res = blend ? 0.5 * (rA + rB) : rA;
    fnBc[((size_t)f * CAP + q) * CC + tid] = res;
    red[tid] = (float)fabs(res - fnA[(size_t)i * CC + tid]);
    __syncthreads();
    for (int s = 128; s > 0; s >>= 1) {
      if (tid < s) red[tid] = fmaxf(red[tid], red[tid + s]);
      __syncthreads();
    }
    if (tid == 0) atomicMax(&maxd[f], __float_as_uint(red[0]));
    __syncthreads();
  }
}

// ---------------- gated corr accumulate (sequential per fork: no races) ----------------
__global__ void corr_aff(const double* __restrict__ fnA, const double* __restrict__ fnBc,
                         double* __restrict__ corr, const unsigned* __restrict__ maxd,
                         const int* __restrict__ forks, int f,
                         const int* __restrict__ afflist, const int* __restrict__ affcnt) {
  if (forks[f] < 0) return;
  if (__uint_as_float(maxd[f]) > DGATE) return;
  const int cnt = min(affcnt[f], CAP);
  const int tid = threadIdx.x;
#pragma unroll 1
  for (int q = blockIdx.x; q < cnt; q += 128) {
    const int i = afflist[(size_t)f * CAP + q];
    corr[(size_t)i * CC + tid] +=
        0.5 * (fnBc[((size_t)f * CAP + q) * CC + tid] - fnA[(size_t)i * CC + tid]);
  }
}

// ---------------- init corr + maxd + affcnt ----------------
__global__ void zero_init(double* __restrict__ corr, unsigned* __restrict__ maxd,
                          int* __restrict__ affcnt) {
  const size_t e = (size_t)blockIdx.x * 256 + threadIdx.x;
  corr[e] = 0.0;
  if (blockIdx.x == 0 && threadIdx.x < NF) {
    maxd[threadIdx.x] = 0u;
    affcnt[threadIdx.x] = 0;
  }
}

// ---------------- out = fA + corr ----------------
__global__ void final_write(const double* __restrict__ fA, const double* __restrict__ corr,
                            float* __restrict__ out) {
  const size_t e = (size_t)blockIdx.x * 256 + threadIdx.x;
  out[e] = (float)(fA[e] + corr[e]);
}

extern "C" void kernel_launch(void* const* d_in, const int* in_sizes, int n_in,
                              void* d_out, int out_size, void* d_ws, size_t ws_size,
                              hipStream_t stream) {
  const float* x0  = (const float*)d_in[0];
  const float* W   = (const float*)d_in[1];
  const float* a_s = (const float*)d_in[2];
  const float* a_d = (const float*)d_in[3];
  const float* b   = (const float*)d_in[4];
  float* out = (float*)d_out;

  char* ws = (char*)d_ws;
  double* xd0   = (double*)ws;  ws += (size_t)NN * CC * 8;   // 16 MB
  double* x1A   = (double*)ws;  ws += (size_t)NN * CC * 8;   // 16 MB
  double* h     = (double*)ws;  ws += (size_t)NN * CC * 8;   // 16 MB
  double* fnA   = (double*)ws;  ws += (size_t)NN * CC * 8;   // 16 MB
  double* corr  = (double*)ws;  ws += (size_t)NN * CC * 8;   // 16 MB
  double* fnBc  = (double*)ws;  ws += (size_t)NF * CAP * CC * 8;   // 12.6 MB
  ushort_t* xb0 = (ushort_t*)ws; ws += (size_t)NN * CC * 2;  // 4 MB
  ushort_t* xbA = (ushort_t*)ws; ws += (size_t)NN * CC * 2;  // 4 MB
  float* sq0    = (float*)ws;   ws += (size_t)NN * 4;
  float* sqA    = (float*)ws;   ws += (size_t)NN * 4;
  double* als   = (double*)ws;  ws += (size_t)NN * 8;
  double* ald   = (double*)ws;  ws += (size_t)NN * 8;
  double* gapd  = (double*)ws;  ws += (size_t)NN * 8;
  double* gapdB3= (double*)ws;  ws += (size_t)NF * NN * 8;
  double* dmB3  = (double*)ws;  ws += (size_t)NF * NN * 8;
  int*   cand   = (int*)ws;     ws += (size_t)NN * NC * 4;   // 6 MB
  int*   kj     = (int*)ws;     ws += (size_t)NN * KE * 4;
  double* kd    = (double*)ws;  ws += (size_t)NN * KE * 8;
  int*   kbj3   = (int*)ws;     ws += (size_t)NF * NN * K17 * 4;
  int*   afflist= (int*)ws;     ws += (size_t)NF * CAP * 4;
  double* rowB  = (double*)ws;  ws += (size_t)NF * CC * 8;
  double* hm3   = (double*)ws;  ws += (size_t)NF * CC * 8;
  double* alsm3 = (double*)ws;  ws += 64 * 8;
  double* aldm3 = (double*)ws;  ws += 64 * 8;
  int*   forks  = (int*)ws;     ws += 64;
  unsigned* maxd = (unsigned*)ws; ws += 64;
  int*   affcnt = (int*)ws;     ws += 64;

  const int NE = NN * CC / 256;

  // ---- layer 1 ----
  xprep_kernel<<<NN, 256, 0, stream>>>(x0, xd0, xb0, sq0);
  hgemm64_kernel<<<NN / 16, 256, 0, stream>>>(xd0, W, h);
  alpha64_kernel<<<NN / 4, 256, 0, stream>>>(h, a_s, a_d, als, ald);
  screen_bf16<<<(NN / 16) * EI, 64, 0, stream>>>(xb0, sq0, cand);
  refine192<<<NN, 256, 0, stream>>>(xd0, cand, kj, kd, gapd);
  agg_blend<<<NN, 256, 0, stream>>>(xd0, h, kj, KE, gapd, als, ald, b,
                                    0.0, x1A, xbA, sqA, 1);
  select_forks<<<1, 64, 0, stream>>>(gapd, forks);
  fork_rowB<<<NF, 256, 0, stream>>>(xd0, h, kj, als, ald, b, forks, rowB);
  zero_init<<<NE, 256, 0, stream>>>(corr, maxd, affcnt);

  // ---- layer 2, branch A ----
  hgemm64_kernel<<<NN / 16, 256, 0, stream>>>(x1A, W + (size_t)CC * CC, h);
  alpha64_kernel<<<NN / 4, 256, 0, stream>>>(h, a_s + CC, a_d + CC, als, ald);
  screen_bf16<<<(NN / 16) * EI, 64, 0, stream>>>(xbA, sqA, cand);
  refine192<<<NN, 256, 0, stream>>>(x1A, cand, kj, kd, gapd);
  agg_blend<<<NN, 256, 0, stream>>>(x1A, h, kj, KE, gapd, als, ald, b + CC,
                                    TAU_L2, fnA, (ushort_t*)0, (float*)0, 0);

  // ---- layer 2, f-folded incremental branch B (affected rows only) ----
  fork_hm_alpha<<<NF, 256, 0, stream>>>(rowB, W + (size_t)CC * CC, a_s + CC, a_d + CC,
                                        forks, hm3, alsm3, aldm3);
  fork_dm<<<(NN / 256) * NF, 256, 0, stream>>>(x1A, rowB, forks, dmB3);
  fork_update_knn<<<(NN / 4) * NF, 256, 0, stream>>>(kj, kd, dmB3, forks, kbj3, gapdB3,
                                                     afflist, affcnt);
  fork_row_m_knn<<<NF, 256, 0, stream>>>(dmB3, forks, kbj3, gapdB3, afflist, affcnt);
  fork_agg_aff<<<128 * NF, 256, 0, stream>>>(x1A, h, kbj3, gapdB3, als, ald, alsm3, aldm3,
                                             hm3, rowB, b + CC, forks, afflist, affcnt,
                                             fnA, fnBc, maxd);
  for (int f = 0; f < NF; ++f)
    corr_aff<<<128, 256, 0, stream>>>(fnA, fnBc, corr, maxd, forks, f, afflist, affcnt);

  final_write<<<NE, 256, 0, stream>>>(fnA, corr, out);
}

// Round 22
// 2055.686 us; speedup vs baseline: 1.2867x; 1.2867x over previous
//
#include <hip/hip_runtime.h>
#include <hip/hip_bf16.h>
#include <math.h>

#define NN 8192
#define CC 256
#define KK 16
#define K17 17
#define KE 20           // extracted+stored per row
#define EI 8            // j-eighths in screening
#define NCH 24          // candidates kept per eighth
#define NC (EI * NCH)   // 192 candidates per row
#define NF 3            // layer-1 fork rows
#define CAP 2048        // max affected rows per fork
#define TAUF 1e-2
#define TAU_L2 4e-3
#define DGATE 0.21f
#define LLEN 8

typedef unsigned long long ull;
typedef unsigned short ushort_t;
typedef short bf16x8 __attribute__((ext_vector_type(8)));
typedef float f32x4 __attribute__((ext_vector_type(4)));

__device__ inline double shfl_xor_d(double x, int m) {
  union { double d; int i[2]; } u;
  u.d = x;
  u.i[0] = __shfl_xor(u.i[0], m);
  u.i[1] = __shfl_xor(u.i[1], m);
  return u.d;
}

// ---------------- x0 prep: promote + bf16 + fp32 row-sq (screening-only) ----------------
__global__ void xprep_kernel(const float* __restrict__ x, double* __restrict__ xd,
                             ushort_t* __restrict__ xb, float* __restrict__ sq) {
  __shared__ float red[256];
  const int i = blockIdx.x;
  const int tid = threadIdx.x;
  const float v = x[(size_t)i * CC + tid];
  xd[(size_t)i * CC + tid] = (double)v;
  __hip_bfloat16 hb = __float2bfloat16(v);
  xb[(size_t)i * CC + tid] = *(ushort_t*)&hb;
  red[tid] = v * v;
  __syncthreads();
  for (int s = 128; s > 0; s >>= 1) {
    if (tid < s) red[tid] += red[tid + s];
    __syncthreads();
  }
  if (tid == 0) sq[i] = red[0];
}

// ---------------- h = xd @ W : full fp64 ----------------
__global__ void hgemm64_kernel(const double* __restrict__ xd, const float* __restrict__ W,
                               double* __restrict__ h) {
  __shared__ double xs[16][CC];
  const int tid = threadIdx.x;
  const int n0 = blockIdx.x * 16;
#pragma unroll
  for (int r = 0; r < 16; ++r) xs[r][tid] = xd[(size_t)(n0 + r) * CC + tid];
  __syncthreads();
  double acc[16];
#pragma unroll
  for (int n = 0; n < 16; ++n) acc[n] = 0.0;
  const float* wp = W + tid;
  for (int k = 0; k < CC; ++k) {
    const double w = (double)wp[(size_t)k * CC];
#pragma unroll
    for (int n = 0; n < 16; ++n) acc[n] += xs[n][k] * w;
  }
#pragma unroll
  for (int n = 0; n < 16; ++n) h[(size_t)(n0 + n) * CC + tid] = acc[n];
}

// ---------------- alpha dots, fp64, one wave per row ----------------
__global__ void alpha64_kernel(const double* __restrict__ h, const float* __restrict__ a_s,
                               const float* __restrict__ a_d, double* __restrict__ als,
                               double* __restrict__ ald) {
  int row = blockIdx.x * 4 + (threadIdx.x >> 6);
  int lane = threadIdx.x & 63;
  const double* hp = h + (size_t)row * CC + 4 * lane;
  double s = 0.0, t = 0.0;
#pragma unroll
  for (int q = 0; q < 4; ++q) {
    const double hv = hp[q];
    s += hv * (double)a_s[4 * lane + q];
    t += hv * (double)a_d[4 * lane + q];
  }
#pragma unroll
  for (int d = 1; d < 64; d <<= 1) {
    s += shfl_xor_d(s, d);
    t += shfl_xor_d(t, d);
  }
  if (lane == 0) { als[row] = s; ald[row] = t; }
}

// ---------------- bf16 MFMA screening v5: 1-wave blocks, j-eighths ----------------
__launch_bounds__(64, 1)
__global__ void screen_bf16(const ushort_t* __restrict__ xb, const float* __restrict__ sq,
                            int* __restrict__ cand) {
  const int lane = threadIdx.x;
  const int g4   = lane >> 4;
  const int l16  = lane & 15;
  const int tile = blockIdx.x >> 3;
  const int eighth = blockIdx.x & 7;
  const int i0   = tile * 16;

  bf16x8 af[8];
  {
    const ushort_t* ap = xb + (size_t)(i0 + l16) * CC + 8 * g4;
#pragma unroll
    for (int ks = 0; ks < 8; ++ks) af[ks] = *(const bf16x8*)(ap + ks * 32);
  }
  float sqi[4];
#pragma unroll
  for (int r = 0; r < 4; ++r) sqi[r] = sq[i0 + 4 * g4 + r];

  float ld[4][LLEN]; int lj[4][LLEN];
#pragma unroll
  for (int r = 0; r < 4; ++r)
#pragma unroll
    for (int s = 0; s < LLEN; ++s) { ld[r][s] = INFINITY; lj[r][s] = 0x7fffffff; }

  const int jbeg = eighth * (NN / EI);
#pragma unroll 1
  for (int t = 0; t < (NN / EI) / 64; ++t) {
    const int j0 = jbeg + t * 64;
#pragma unroll
    for (int jt = 0; jt < 4; ++jt) {
      f32x4 acc = {0.f, 0.f, 0.f, 0.f};
      const ushort_t* bp = xb + (size_t)(j0 + jt * 16 + l16) * CC + 8 * g4;
#pragma unroll
      for (int ks = 0; ks < 8; ++ks) {
        const bf16x8 bv = *(const bf16x8*)(bp + ks * 32);
        acc = __builtin_amdgcn_mfma_f32_16x16x32_bf16(af[ks], bv, acc, 0, 0, 0);
      }
      const int jc = j0 + jt * 16 + l16;
      const float sqj = sq[jc];
#pragma unroll
      for (int r = 0; r < 4; ++r) {
        const float dv = (sqi[r] + sqj) - 2.f * acc[r];
        const bool self = (jc == i0 + 4 * g4 + r);
        if (!self && (dv < ld[r][LLEN - 1] ||
                      (dv == ld[r][LLEN - 1] && jc < lj[r][LLEN - 1]))) {
          ld[r][LLEN - 1] = dv; lj[r][LLEN - 1] = jc;
#pragma unroll
          for (int s = LLEN - 1; s > 0; --s) {
            const bool sw = (ld[r][s] < ld[r][s - 1]) ||
                            (ld[r][s] == ld[r][s - 1] && lj[r][s] < lj[r][s - 1]);
            const float tv = ld[r][s - 1]; const int jv = lj[r][s - 1];
            ld[r][s - 1] = sw ? ld[r][s] : ld[r][s - 1];
            lj[r][s - 1] = sw ? lj[r][s] : lj[r][s - 1];
            ld[r][s] = sw ? tv : ld[r][s];
            lj[r][s] = sw ? jv : lj[r][s];
          }
        }
      }
    }
  }

#pragma unroll
  for (int r = 0; r < 4; ++r) {
    const int rr = 4 * g4 + r;
#pragma unroll 1
    for (int s = 0; s < NCH; ++s) {
      float hd = ld[r][0]; int hj = lj[r][0];
#pragma unroll
      for (int dlt = 1; dlt < 16; dlt <<= 1) {
        const float od = __shfl_xor(hd, dlt);
        const int oj = __shfl_xor(hj, dlt);
        if (od < hd || (od == hd && oj < hj)) { hd = od; hj = oj; }
      }
      if (ld[r][0] == hd && lj[r][0] == hj) {
#pragma unroll
        for (int s2 = 0; s2 < LLEN - 1; ++s2) {
          ld[r][s2] = ld[r][s2 + 1]; lj[r][s2] = lj[r][s2 + 1];
        }
        ld[r][LLEN - 1] = INFINITY; lj[r][LLEN - 1] = 0x7fffffff;
      }
      if (l16 == 0) cand[(size_t)(i0 + rr) * NC + eighth * NCH + s] = hj;
    }
  }
}

// ---------------- refine v2: wave-coop coalesced fp32-gather, fp64 math ----------------
// One block per row. Wave w handles candidates c = w, w+4, ... Lanes read
// float4 (coalesced), promote to fp64 (exact), fixed butterfly reduction.
__launch_bounds__(256, 1)
__global__ void refine192c(const float* __restrict__ x32, const int* __restrict__ cand,
                           int* __restrict__ kj, double* __restrict__ kd,
                           double* __restrict__ gapd) {
  __shared__ double rd[NC];
  __shared__ int    rj[NC];
  __shared__ float  xi[CC];
  const int row = blockIdx.x;
  const int tid = threadIdx.x;
  const int wave = tid >> 6;
  const int lane = tid & 63;
  xi[tid] = x32[(size_t)row * CC + tid];
  __syncthreads();
#pragma unroll 1
  for (int c = wave; c < NC; c += 4) {
    const int j = cand[(size_t)row * NC + c];
    const f32x4 xjv = *(const f32x4*)(x32 + (size_t)j * CC + 4 * lane);
    const f32x4 xiv = *(const f32x4*)(&xi[4 * lane]);
    double p = 0.0;
    const double t0 = (double)xiv[0] - (double)xjv[0]; p = fma(t0, t0, p);
    const double t1 = (double)xiv[1] - (double)xjv[1]; p = fma(t1, t1, p);
    const double t2 = (double)xiv[2] - (double)xjv[2]; p = fma(t2, t2, p);
    const double t3 = (double)xiv[3] - (double)xjv[3]; p = fma(t3, t3, p);
#pragma unroll
    for (int d = 1; d < 64; d <<= 1) p += shfl_xor_d(p, d);
    if (lane == 0) { rd[c] = p; rj[c] = j; }
  }
  __syncthreads();
  if (tid < 64) {
    volatile double* vd = rd;
    volatile int*    vj = rj;
    double d16 = 0.0, d17 = 0.0;
    for (int s = 0; s < KE; ++s) {
      double bv = 1e300; int bj = 0x7fffffff; int bp = -1;
      for (int e = tid; e < NC; e += 64) {
        const double v = vd[e];
        const int jv = vj[e];
        if (v < bv || (v == bv && jv < bj)) { bv = v; bj = jv; bp = e; }
      }
#pragma unroll
      for (int dlt = 1; dlt < 64; dlt <<= 1) {
        const double ov = shfl_xor_d(bv, dlt);
        const int oj = __shfl_xor(bj, dlt);
        const int op = __shfl_xor(bp, dlt);
        if (ov < bv || (ov == bv && oj < bj)) { bv = ov; bj = oj; bp = op; }
      }
      if (tid == 0) {
        kj[(size_t)row * KE + s] = bj;
        kd[(size_t)row * KE + s] = bv;
        vd[bp] = 1e300;
        vj[bp] = 0x7fffffff;
      }
      if (s == KK - 1) d16 = bv;
      if (s == KK)     d17 = bv;
    }
    if (tid == 0) gapd[row] = d17 - d16;
  }
}

// ---------------- dual-branch softmax+aggregate + gated blend (+aux epilogue) ----------------
__global__ void agg_blend(const double* __restrict__ xin, const double* __restrict__ h,
                          const int* __restrict__ knn, int ldk, const double* __restrict__ gapd,
                          const double* __restrict__ als, const double* __restrict__ ald,
                          const float* __restrict__ bias, double tau,
                          double* __restrict__ xd_out, ushort_t* __restrict__ xb_out,
                          float* __restrict__ sq_out, float* __restrict__ x32_out,
                          int do_aux) {
  const int i = blockIdx.x;
  const int tid = threadIdx.x;
  __shared__ int idx[K17 + 1];
  __shared__ double attA[K17 + 1];
  __shared__ double attB[K17 + 1];
  __shared__ float red[256];
  if (tid < K17) idx[tid] = knn[(size_t)i * ldk + tid];
  if (tid == K17) idx[K17] = i;
  __syncthreads();
  if (tid == 0) {
    double e[K17 + 1];
#pragma unroll
    for (int l = 0; l < K17 + 1; ++l) {
      const double t = als[idx[l]] + ald[i];
      e[l] = (t >= 0.0) ? t : 0.2 * t;
    }
    {  // branch A: {0..15} + self
      double mx = e[K17];
#pragma unroll
      for (int l = 0; l < KK; ++l) mx = fmax(mx, e[l]);
      double den = 0.0, p[K17 + 1];
#pragma unroll
      for (int l = 0; l < KK; ++l) { p[l] = exp(e[l] - mx); den += p[l]; }
      p[K17] = exp(e[K17] - mx); den += p[K17];
      const double inv = 1.0 / den;
#pragma unroll
      for (int l = 0; l < K17 + 1; ++l) attA[l] = 0.0;
#pragma unroll
      for (int l = 0; l < KK; ++l) attA[l] = p[l] * inv;
      attA[K17] = p[K17] * inv;
    }
    {  // branch B: {0..14, 16} + self
      double mx = e[K17];
#pragma unroll
      for (int l = 0; l < KK - 1; ++l) mx = fmax(mx, e[l]);
      mx = fmax(mx, e[KK]);
      double den = 0.0, p[K17 + 1];
#pragma unroll
      for (int l = 0; l < KK - 1; ++l) { p[l] = exp(e[l] - mx); den += p[l]; }
      p[KK] = exp(e[KK] - mx); den += p[KK];
      p[K17] = exp(e[K17] - mx); den += p[K17];
      const double inv = 1.0 / den;
#pragma unroll
      for (int l = 0; l < K17 + 1; ++l) attB[l] = 0.0;
#pragma unroll
      for (int l = 0; l < KK - 1; ++l) attB[l] = p[l] * inv;
      attB[KK] = p[KK] * inv;
      attB[K17] = p[K17] * inv;
    }
  }
  __syncthreads();
  double outA = 0.0, outB = 0.0;
#pragma unroll 1
  for (int l = 0; l < K17 + 1; ++l) {
    const double hv = h[(size_t)idx[l] * CC + tid];
    outA += attA[l] * hv;
    outB += attB[l] * hv;
  }
  const double xv = xin[(size_t)i * CC + tid];
  const double bb = (double)bias[tid];
  const double rA = xv + fmax(outA + bb, 0.0);
  const double rB = xv + fmax(outB + bb, 0.0);
  red[tid] = (float)fabs(rA - rB);
  __syncthreads();
  for (int s = 128; s > 0; s >>= 1) {
    if (tid < s) red[tid] = fmaxf(red[tid], red[tid + s]);
    __syncthreads();
  }
  const bool blend = (gapd[i] < tau) && (red[0] <= DGATE);
  const double res = blend ? 0.5 * (rA + rB) : rA;
  xd_out[(size_t)i * CC + tid] = res;
  if (do_aux) {   // bf16 + fp32 mirror + row-sq for next layer's screening/refine
    const float x32 = (float)res;
    __hip_bfloat16 hb = __float2bfloat16(x32);
    xb_out[(size_t)i * CC + tid] = *(ushort_t*)&hb;
    x32_out[(size_t)i * CC + tid] = x32;
    __syncthreads();
    red[tid] = x32 * x32;
    __syncthreads();
    for (int s = 128; s > 0; s >>= 1) {
      if (tid < s) red[tid] += red[tid + s];
      __syncthreads();
    }
    if (tid == 0) sq_out[i] = red[0];
  }
}

// ---------------- pick NF smallest layer-1 gaps (< TAUF) ----------------
__global__ void select_forks(const double* __restrict__ gapd, int* __restrict__ forks) {
  const int lane = threadIdx.x;
  int ch0 = -2, ch1 = -2;
  for (int f = 0; f < NF; ++f) {
    double bv = TAUF; int bi = 0x7fffffff;
    for (int i = lane; i < NN; i += 64) {
      if (i == ch0 || i == ch1) continue;
      const double v = gapd[i];
      if (v < bv || (v == bv && i < bi)) { bv = v; bi = i; }
    }
#pragma unroll
    for (int d = 1; d < 64; d <<= 1) {
      const double ov = shfl_xor_d(bv, d);
      const int oi = __shfl_xor(bi, d);
      if (ov < bv || (ov == bv && oi < bi)) { bv = ov; bi = oi; }
    }
    const int win = (bi == 0x7fffffff) ? -1 : bi;
    if (lane == 0) forks[f] = win;
    if (f == 0) ch0 = win;
    if (f == 1) ch1 = win;
  }
}

// ---------------- branch-B layer-1 output row per fork ----------------
__global__ void fork_rowB(const double* __restrict__ xin, const double* __restrict__ h,
                          const int* __restrict__ knn, const double* __restrict__ als,
                          const double* __restrict__ ald, const float* __restrict__ bias,
                          const int* __restrict__ forks, double* __restrict__ rowB) {
  const int f = blockIdx.x;
  const int tid = threadIdx.x;
  const int i = forks[f];
  if (i < 0) { rowB[(size_t)f * CC + tid] = 0.0; return; }
  __shared__ int idx[K17 + 1];
  __shared__ double attB[K17 + 1];
  if (tid < K17) idx[tid] = knn[(size_t)i * KE + tid];
  if (tid == K17) idx[K17] = i;
  __syncthreads();
  if (tid == 0) {
    double e[K17 + 1];
#pragma unroll
    for (int l = 0; l < K17 + 1; ++l) {
      const double t = als[idx[l]] + ald[i];
      e[l] = (t >= 0.0) ? t : 0.2 * t;
    }
    double mx = e[K17];
#pragma unroll
    for (int l = 0; l < KK - 1; ++l) mx = fmax(mx, e[l]);
    mx = fmax(mx, e[KK]);
    double den = 0.0, p[K17 + 1];
#pragma unroll
    for (int l = 0; l < KK - 1; ++l) { p[l] = exp(e[l] - mx); den += p[l]; }
    p[KK] = exp(e[KK] - mx); den += p[KK];
    p[K17] = exp(e[K17] - mx); den += p[K17];
    const double inv = 1.0 / den;
#pragma unroll
    for (int l = 0; l < K17 + 1; ++l) attB[l] = 0.0;
#pragma unroll
    for (int l = 0; l < KK - 1; ++l) attB[l] = p[l] * inv;
    attB[KK] = p[KK] * inv;
    attB[K17] = p[K17] * inv;
  }
  __syncthreads();
  double outB = 0.0;
#pragma unroll 1
  for (int l = 0; l < K17 + 1; ++l)
    outB += attB[l] * h[(size_t)idx[l] * CC + tid];
  rowB[(size_t)f * CC + tid] =
      xin[(size_t)i * CC + tid] + fmax(outB + (double)bias[tid], 0.0);
}

// ---------------- f-folded: hm = rowB @ W2 + als_m/ald_m ----------------
__global__ void fork_hm_alpha(const double* __restrict__ rowB, const float* __restrict__ W2,
                              const float* __restrict__ a_s2, const float* __restrict__ a_d2,
                              const int* __restrict__ forks,
                              double* __restrict__ hm3, double* __restrict__ alsm3,
                              double* __restrict__ aldm3) {
  const int f = blockIdx.x;
  const int m = forks[f];
  if (m < 0) return;
  __shared__ double rb[CC];
  __shared__ double hs[CC];
  const int tid = threadIdx.x;
  rb[tid] = rowB[(size_t)f * CC + tid];
  __syncthreads();
  double acc = 0.0;
  const float* wp = W2 + tid;
  for (int k = 0; k < CC; ++k) {
    const double w = (double)wp[(size_t)k * CC];
    acc += rb[k] * w;
  }
  hm3[(size_t)f * CC + tid] = acc;
  hs[tid] = acc;
  __syncthreads();
  if (tid < 64) {
    const double* hp = hs + 4 * tid;
    double s = 0.0, t = 0.0;
#pragma unroll
    for (int q = 0; q < 4; ++q) {
      const double hv = hp[q];
      s += hv * (double)a_s2[4 * tid + q];
      t += hv * (double)a_d2[4 * tid + q];
    }
#pragma unroll
    for (int d = 1; d < 64; d <<= 1) {
      s += shfl_xor_d(s, d);
      t += shfl_xor_d(t, d);
    }
    if (tid == 0) { alsm3[f] = s; aldm3[f] = t; }
  }
}

// ---------------- f-folded: dmB3[f][i] = ||x1A_i - rowB_f||^2 ----------------
__global__ void fork_dm(const double* __restrict__ x1A, const double* __restrict__ rowB,
                        const int* __restrict__ forks, double* __restrict__ dmB3) {
  const int f = blockIdx.x / (NN / 256);
  const int ib = blockIdx.x % (NN / 256);
  const int m = forks[f];
  if (m < 0) return;
  __shared__ double rb[CC];
  const int tid = threadIdx.x;
  rb[tid] = rowB[(size_t)f * CC + tid];
  __syncthreads();
  const int i = ib * 256 + tid;
  const double* xi = x1A + (size_t)i * CC;
  double acc = 0.0;
#pragma unroll 4
  for (int k = 0; k < CC; ++k) {
    const double t = xi[k] - rb[k];
    acc = fma(t, t, acc);
  }
  dmB3[(size_t)f * NN + i] = acc;
}

// ---------------- f-folded: incremental top-17, affected rows only ----------------
__global__ void fork_update_knn(const int* __restrict__ kj, const double* __restrict__ kd,
                                const double* __restrict__ dmB3, const int* __restrict__ forks,
                                int* __restrict__ kbj3, double* __restrict__ gapdB3,
                                int* __restrict__ afflist, int* __restrict__ affcnt) {
  const int f = blockIdx.x / (NN / 4);
  const int rb = blockIdx.x % (NN / 4);
  const int m = forks[f];
  if (m < 0) return;
  const int row = rb * 4 + (threadIdx.x >> 6);
  const int lane = threadIdx.x & 63;
  if (row == m) return;
  double d = 1e300;
  int j = 0x7fffffff;
  if (lane < KE) { j = kj[(size_t)row * KE + lane]; d = kd[(size_t)row * KE + lane]; }
  const ull pres = __ballot(lane < KE && j == m);
  const double dm = dmB3[(size_t)f * NN + row];
  const double k17d = kd[(size_t)row * KE + K17 - 1];
  const int    k17j = kj[(size_t)row * KE + K17 - 1];
  const bool ins = (dm < k17d) || (dm == k17d && m < k17j);
  if (pres == 0ull && !ins) return;          // unaffected: fB == fA bit-identical
  if (lane < KE && j == m) d = dm;
  if (lane == KE && pres == 0ull) { j = m; d = dm; }
  double d16 = 0.0, d17 = 0.0;
#pragma unroll 1
  for (int s = 0; s < K17; ++s) {
    double v = d; int e = j;
#pragma unroll
    for (int dlt = 1; dlt < 64; dlt <<= 1) {
      const double ov = shfl_xor_d(v, dlt);
      const int oe = __shfl_xor(e, dlt);
      if (ov < v || (ov == v && oe < e)) { v = ov; e = oe; }
    }
    if (j == e) d = 1e300;
    if (lane == 0) kbj3[((size_t)f * NN + row) * K17 + s] = e;
    if (s == KK - 1) d16 = v;
    if (s == KK)     d17 = v;
  }
  if (lane == 0) {
    gapdB3[(size_t)f * NN + row] = d17 - d16;
    const int slot = atomicAdd(&affcnt[f], 1);
    if (slot < CAP) afflist[(size_t)f * CAP + slot] = row;
  }
}

// ---------------- f-folded: row m's own top-17 over dmB ----------------
__launch_bounds__(256, 1)
__global__ void fork_row_m_knn(const double* __restrict__ dmB3, const int* __restrict__ forks,
                               int* __restrict__ kbj3, double* __restrict__ gapdB3,
                               int* __restrict__ afflist, int* __restrict__ affcnt) {
  const int f = blockIdx.x;
  const int m = forks[f];
  if (m < 0) return;
  __shared__ double md[256 * 18];
  __shared__ int    mj[256 * 18];
  const int tid = threadIdx.x;
  double td[18]; int tj[18];
#pragma unroll
  for (int s = 0; s < 18; ++s) { td[s] = 1e300; tj[s] = 0x7fffffff; }
  for (int j = tid; j < NN; j += 256) {
    if (j == m) continue;
    const double d = dmB3[(size_t)f * NN + j];
    if (d < td[17] || (d == td[17] && j < tj[17])) {
      td[17] = d; tj[17] = j;
#pragma unroll
      for (int s = 17; s > 0; --s) {
        const bool sw = (td[s] < td[s - 1]) ||
                        (td[s] == td[s - 1] && tj[s] < tj[s - 1]);
        const double tv = td[s - 1]; const int jv = tj[s - 1];
        td[s - 1] = sw ? td[s] : td[s - 1];
        tj[s - 1] = sw ? tj[s] : tj[s - 1];
        td[s] = sw ? tv : td[s];
        tj[s] = sw ? jv : tj[s];
      }
    }
  }
#pragma unroll
  for (int s = 0; s < 18; ++s) { md[tid * 18 + s] = td[s]; mj[tid * 18 + s] = tj[s]; }
  __syncthreads();
  if (tid < 64) {
    volatile double* vmd = md;
    volatile int*    vmj = mj;
    double d16 = 0.0, d17 = 0.0;
    for (int r = 0; r < K17; ++r) {
      double bv = 1e300; int bj = 0x7fffffff; int bp = -1;
      for (int e = tid; e < 256 * 18; e += 64) {
        const double v = vmd[e];
        const int jv = vmj[e];
        if (v < bv || (v == bv && jv < bj)) { bv = v; bj = jv; bp = e; }
      }
#pragma unroll
      for (int dlt = 1; dlt < 64; dlt <<= 1) {
        const double ov = shfl_xor_d(bv, dlt);
        const int oj = __shfl_xor(bj, dlt);
        const int op = __shfl_xor(bp, dlt);
        if (ov < bv || (ov == bv && oj < bj)) { bv = ov; bj = oj; bp = op; }
      }
      if (tid == 0) {
        kbj3[((size_t)f * NN + m) * K17 + r] = bj;
        vmd[bp] = 1e300;
        vmj[bp] = 0x7fffffff;
      }
      if (r == KK - 1) d16 = bv;
      if (r == KK)     d17 = bv;
    }
    if (tid == 0) {
      gapdB3[(size_t)f * NN + m] = d17 - d16;
      const int slot = atomicAdd(&affcnt[f], 1);
      if (slot < CAP) afflist[(size_t)f * CAP + slot] = m;
    }
  }
}

// ---------------- f-folded: agg over affected rows -> compact fnBc + maxd ----------------
__global__ void fork_agg_aff(const double* __restrict__ x1A, const double* __restrict__ h,
                             const int* __restrict__ kbj3, const double* __restrict__ gapdB3,
                             const double* __restrict__ als, const double* __restrict__ ald,
                             const double* __restrict__ alsm3, const double* __restrict__ aldm3,
                             const double* __restrict__ hm3, const double* __restrict__ rowB,
                             const float* __restrict__ bias, const int* __restrict__ forks,
                             const int* __restrict__ afflist, const int* __restrict__ affcnt,
                             const double* __restrict__ fnA, double* __restrict__ fnBc,
                             unsigned* __restrict__ maxd) {
  const int f = blockIdx.x >> 7;          // 128 blocks per fork
  const int qb = blockIdx.x & 127;
  const int m = forks[f];
  if (m < 0) return;
  const int cnt = min(affcnt[f], CAP);
  const int tid = threadIdx.x;
  __shared__ int idx[K17 + 1];
  __shared__ double attA[K17 + 1];
  __shared__ double attB[K17 + 1];
  __shared__ float red[256];
#pragma unroll 1
  for (int q = qb; q < cnt; q += 128) {
    const int i = afflist[(size_t)f * CAP + q];
    if (tid < K17) idx[tid] = kbj3[((size_t)f * NN + i) * K17 + tid];
    if (tid == K17) idx[K17] = i;
    __syncthreads();
    if (tid == 0) {
      const double aldi = (i == m) ? aldm3[f] : ald[i];
      double e[K17 + 1];
#pragma unroll
      for (int l = 0; l < K17 + 1; ++l) {
        const int ix = idx[l];
        const double a = (ix == m) ? alsm3[f] : als[ix];
        const double t = a + aldi;
        e[l] = (t >= 0.0) ? t : 0.2 * t;
      }
      {
        double mx = e[K17];
#pragma unroll
        for (int l = 0; l < KK; ++l) mx = fmax(mx, e[l]);
        double den = 0.0, p[K17 + 1];
#pragma unroll
        for (int l = 0; l < KK; ++l) { p[l] = exp(e[l] - mx); den += p[l]; }
        p[K17] = exp(e[K17] - mx); den += p[K17];
        const double inv = 1.0 / den;
#pragma unroll
        for (int l = 0; l < K17 + 1; ++l) attA[l] = 0.0;
#pragma unroll
        for (int l = 0; l < KK; ++l) attA[l] = p[l] * inv;
        attA[K17] = p[K17] * inv;
      }
      {
        double mx = e[K17];
#pragma unroll
        for (int l = 0; l < KK - 1; ++l) mx = fmax(mx, e[l]);
        mx = fmax(mx, e[KK]);
        double den = 0.0, p[K17 + 1];
#pragma unroll
        for (int l = 0; l < KK - 1; ++l) { p[l] = exp(e[l] - mx); den += p[l]; }
        p[KK] = exp(e[KK] - mx); den += p[KK];
        p[K17] = exp(e[K17] - mx); den += p[K17];
        const double inv = 1.0 / den;
#pragma unroll
        for (int l = 0; l < K17 + 1; ++l) attB[l] = 0.0;
#pragma unroll
        for (int l = 0; l < KK - 1; ++l) attB[l] = p[l] * inv;
        attB[KK] = p[KK] * inv;
        attB[K17] = p[K17] * inv;
      }
    }
    __syncthreads();
    double outA = 0.0, outB = 0.0;
#pragma unroll 1
    for (int l = 0; l < K17 + 1; ++l) {
      const int ix = idx[l];
      const double hv = (ix == m) ? hm3[(size_t)f * CC + tid] : h[(size_t)ix * CC + tid];
      outA += attA[l] * hv;
      outB += attB[l] * hv;
    }
    const double xv = (i == m) ? rowB[(size_t)f * CC + tid] : x1A[(size_t)i * CC + tid];
    const double bb = (double)bias[tid];
    const double rA = xv + fmax(outA + bb, 0.0);
    const double rB = xv + fmax(outB + bb, 0.0);
    red[tid] = (float)fabs(rA - rB);
    __syncthreads();
    for (int s = 128; s > 0; s >>= 1) {
      if (tid < s) red[tid] = fmaxf(red[tid], red[tid + s]);
      __syncthreads();
    }
    const bool blend = (gapdB3[(size_t)f * NN + i] < TAU_L2) && (red[0] <= DGATE);
    const double res = blend ? 0.5 * (rA + rB) : rA;
    fnBc[((size_t)f * CAP + q) * CC + tid] = res;
    red[tid] = (float)fabs(res - fnA[(size_t)i * CC + tid]);
    __syncthreads();
    for (int s = 128; s > 0; s >>= 1) {
      if (tid < s) red[tid] = fmaxf(red[tid], red[tid + s]);
      __syncthreads();
    }
    if (tid == 0) atomicMax(&maxd[f], __float_as_uint(red[0]));
    __syncthreads();
  }
}

// ---------------- gated corr accumulate (sequential per fork: no races) ----------------
__global__ void corr_aff(const double* __restrict__ fnA, const double* __restrict__ fnBc,
                         double* __restrict__ corr, const unsigned* __restrict__ maxd,
                         const int* __restrict__ forks, int f,
                         const int* __restrict__ afflist, const int* __restrict__ affcnt) {
  if (forks[f] < 0) return;
  if (__uint_as_float(maxd[f]) > DGATE) return;
  const int cnt = min(affcnt[f], CAP);
  const int tid = threadIdx.x;
#pragma unroll 1
  for (int q = blockIdx.x; q < cnt; q += 128) {
    const int i = afflist[(size_t)f * CAP + q];
    corr[(size_t)i * CC + tid] +=
        0.5 * (fnBc[((size_t)f * CAP + q) * CC + tid] - fnA[(size_t)i * CC + tid]);
  }
}

// ---------------- init corr + maxd + affcnt ----------------
__global__ void zero_init(double* __restrict__ corr, unsigned* __restrict__ maxd,
                          int* __restrict__ affcnt) {
  const size_t e = (size_t)blockIdx.x * 256 + threadIdx.x;
  corr[e] = 0.0;
  if (blockIdx.x == 0 && threadIdx.x < NF) {
    maxd[threadIdx.x] = 0u;
    affcnt[threadIdx.x] = 0;
  }
}

// ---------------- out = fA + corr ----------------
__global__ void final_write(const double* __restrict__ fA, const double* __restrict__ corr,
                            float* __restrict__ out) {
  const size_t e = (size_t)blockIdx.x * 256 + threadIdx.x;
  out[e] = (float)(fA[e] + corr[e]);
}

extern "C" void kernel_launch(void* const* d_in, const int* in_sizes, int n_in,
                              void* d_out, int out_size, void* d_ws, size_t ws_size,
                              hipStream_t stream) {
  const float* x0  = (const float*)d_in[0];
  const float* W   = (const float*)d_in[1];
  const float* a_s = (const float*)d_in[2];
  const float* a_d = (const float*)d_in[3];
  const float* b   = (const float*)d_in[4];
  float* out = (float*)d_out;

  char* ws = (char*)d_ws;
  double* xd0   = (double*)ws;  ws += (size_t)NN * CC * 8;   // 16 MB
  double* x1A   = (double*)ws;  ws += (size_t)NN * CC * 8;   // 16 MB
  double* h     = (double*)ws;  ws += (size_t)NN * CC * 8;   // 16 MB
  double* fnA   = (double*)ws;  ws += (size_t)NN * CC * 8;   // 16 MB
  double* corr  = (double*)ws;  ws += (size_t)NN * CC * 8;   // 16 MB
  double* fnBc  = (double*)ws;  ws += (size_t)NF * CAP * CC * 8;   // 12.6 MB
  float* x32A   = (float*)ws;   ws += (size_t)NN * CC * 4;   // 8 MB
  ushort_t* xb0 = (ushort_t*)ws; ws += (size_t)NN * CC * 2;  // 4 MB
  ushort_t* xbA = (ushort_t*)ws; ws += (size_t)NN * CC * 2;  // 4 MB
  float* sq0    = (float*)ws;   ws += (size_t)NN * 4;
  float* sqA    = (float*)ws;   ws += (size_t)NN * 4;
  double* als   = (double*)ws;  ws += (size_t)NN * 8;
  double* ald   = (double*)ws;  ws += (size_t)NN * 8;
  double* gapd  = (double*)ws;  ws += (size_t)NN * 8;
  double* gapdB3= (double*)ws;  ws += (size_t)NF * NN * 8;
  double* dmB3  = (double*)ws;  ws += (size_t)NF * NN * 8;
  int*   cand   = (int*)ws;     ws += (size_t)NN * NC * 4;   // 6 MB
  int*   kj     = (int*)ws;     ws += (size_t)NN * KE * 4;
  double* kd    = (double*)ws;  ws += (size_t)NN * KE * 8;
  int*   kbj3   = (int*)ws;     ws += (size_t)NF * NN * K17 * 4;
  int*   afflist= (int*)ws;     ws += (size_t)NF * CAP * 4;
  double* rowB  = (double*)ws;  ws += (size_t)NF * CC * 8;
  double* hm3   = (double*)ws;  ws += (size_t)NF * CC * 8;
  double* alsm3 = (double*)ws;  ws += 64 * 8;
  double* aldm3 = (double*)ws;  ws += 64 * 8;
  int*   forks  = (int*)ws;     ws += 64;
  unsigned* maxd = (unsigned*)ws; ws += 64;
  int*   affcnt = (int*)ws;     ws += 64;

  const int NE = NN * CC / 256;

  // ---- layer 1 ----
  xprep_kernel<<<NN, 256, 0, stream>>>(x0, xd0, xb0, sq0);
  hgemm64_kernel<<<NN / 16, 256, 0, stream>>>(xd0, W, h);
  alpha64_kernel<<<NN / 4, 256, 0, stream>>>(h, a_s, a_d, als, ald);
  screen_bf16<<<(NN / 16) * EI, 64, 0, stream>>>(xb0, sq0, cand);
  refine192c<<<NN, 256, 0, stream>>>(x0, cand, kj, kd, gapd);   // fp32 src == exact
  agg_blend<<<NN, 256, 0, stream>>>(xd0, h, kj, KE, gapd, als, ald, b,
                                    0.0, x1A, xbA, sqA, x32A, 1);
  select_forks<<<1, 64, 0, stream>>>(gapd, forks);
  fork_rowB<<<NF, 256, 0, stream>>>(xd0, h, kj, als, ald, b, forks, rowB);
  zero_init<<<NE, 256, 0, stream>>>(corr, maxd, affcnt);

  // ---- layer 2, branch A ----
  hgemm64_kernel<<<NN / 16, 256, 0, stream>>>(x1A, W + (size_t)CC * CC, h);
  alpha64_kernel<<<NN / 4, 256, 0, stream>>>(h, a_s + CC, a_d + CC, als, ald);
  screen_bf16<<<(NN / 16) * EI, 64, 0, stream>>>(xbA, sqA, cand);
  refine192c<<<NN, 256, 0, stream>>>(x32A, cand, kj, kd, gapd);
  agg_blend<<<NN, 256, 0, stream>>>(x1A, h, kj, KE, gapd, als, ald, b + CC,
                                    TAU_L2, fnA, (ushort_t*)0, (float*)0, (float*)0, 0);

  // ---- layer 2, f-folded incremental branch B (affected rows only) ----
  fork_hm_alpha<<<NF, 256, 0, stream>>>(rowB, W + (size_t)CC * CC, a_s + CC, a_d + CC,
                                        forks, hm3, alsm3, aldm3);
  fork_dm<<<(NN / 256) * NF, 256, 0, stream>>>(x1A, rowB, forks, dmB3);
  fork_update_knn<<<(NN / 4) * NF, 256, 0, stream>>>(kj, kd, dmB3, forks, kbj3, gapdB3,
                                                     afflist, affcnt);
  fork_row_m_knn<<<NF, 256, 0, stream>>>(dmB3, forks, kbj3, gapdB3, afflist, affcnt);
  fork_agg_aff<<<128 * NF, 256, 0, stream>>>(x1A, h, kbj3, gapdB3, als, ald, alsm3, aldm3,
                                             hm3, rowB, b + CC, forks, afflist, affcnt,
                                             fnA, fnBc, maxd);
  for (int f = 0; f < NF; ++f)
    corr_aff<<<128, 256, 0, stream>>>(fnA, fnBc, corr, maxd, forks, f, afflist, affcnt);

  final_write<<<NE, 256, 0, stream>>>(fnA, corr, out);
}

// Round 23
// 1850.525 us; speedup vs baseline: 1.4294x; 1.1109x over previous
//
#include <hip/hip_runtime.h>
#include <hip/hip_bf16.h>
#include <math.h>

#define NN 8192
#define CC 256
#define KK 16
#define K17 17
#define KE 20           // extracted+stored per row
#define EI 8            // j-eighths in screening
#define NCH 16          // candidates kept per eighth (P(top-20 loss) ~ 7e-8)
#define NC (EI * NCH)   // 128 candidates per row
#define NF 3            // layer-1 fork rows
#define CAP 2048        // max affected rows per fork
#define TAUF 1e-2
#define TAU_L2 4e-3
#define DGATE 0.21f
#define LLEN 8

typedef unsigned long long ull;
typedef unsigned short ushort_t;
typedef short bf16x8 __attribute__((ext_vector_type(8)));
typedef float f32x4 __attribute__((ext_vector_type(4)));

__device__ inline double shfl_xor_d(double x, int m) {
  union { double d; int i[2]; } u;
  u.d = x;
  u.i[0] = __shfl_xor(u.i[0], m);
  u.i[1] = __shfl_xor(u.i[1], m);
  return u.d;
}

// ---------------- x0 prep: promote + bf16 + fp32 row-sq (screening-only) ----------------
__global__ void xprep_kernel(const float* __restrict__ x, double* __restrict__ xd,
                             ushort_t* __restrict__ xb, float* __restrict__ sq) {
  __shared__ float red[256];
  const int i = blockIdx.x;
  const int tid = threadIdx.x;
  const float v = x[(size_t)i * CC + tid];
  xd[(size_t)i * CC + tid] = (double)v;
  __hip_bfloat16 hb = __float2bfloat16(v);
  xb[(size_t)i * CC + tid] = *(ushort_t*)&hb;
  red[tid] = v * v;
  __syncthreads();
  for (int s = 128; s > 0; s >>= 1) {
    if (tid < s) red[tid] += red[tid + s];
    __syncthreads();
  }
  if (tid == 0) sq[i] = red[0];
}

// ---------------- h = xd @ W : full fp64 ----------------
__global__ void hgemm64_kernel(const double* __restrict__ xd, const float* __restrict__ W,
                               double* __restrict__ h) {
  __shared__ double xs[16][CC];
  const int tid = threadIdx.x;
  const int n0 = blockIdx.x * 16;
#pragma unroll
  for (int r = 0; r < 16; ++r) xs[r][tid] = xd[(size_t)(n0 + r) * CC + tid];
  __syncthreads();
  double acc[16];
#pragma unroll
  for (int n = 0; n < 16; ++n) acc[n] = 0.0;
  const float* wp = W + tid;
  for (int k = 0; k < CC; ++k) {
    const double w = (double)wp[(size_t)k * CC];
#pragma unroll
    for (int n = 0; n < 16; ++n) acc[n] += xs[n][k] * w;
  }
#pragma unroll
  for (int n = 0; n < 16; ++n) h[(size_t)(n0 + n) * CC + tid] = acc[n];
}

// ---------------- alpha dots, fp64, one wave per row ----------------
__global__ void alpha64_kernel(const double* __restrict__ h, const float* __restrict__ a_s,
                               const float* __restrict__ a_d, double* __restrict__ als,
                               double* __restrict__ ald) {
  int row = blockIdx.x * 4 + (threadIdx.x >> 6);
  int lane = threadIdx.x & 63;
  const double* hp = h + (size_t)row * CC + 4 * lane;
  double s = 0.0, t = 0.0;
#pragma unroll
  for (int q = 0; q < 4; ++q) {
    const double hv = hp[q];
    s += hv * (double)a_s[4 * lane + q];
    t += hv * (double)a_d[4 * lane + q];
  }
#pragma unroll
  for (int d = 1; d < 64; d <<= 1) {
    s += shfl_xor_d(s, d);
    t += shfl_xor_d(t, d);
  }
  if (lane == 0) { als[row] = s; ald[row] = t; }
}

// ---------------- bf16 MFMA screening v6: 4 independent waves per block ----------------
// grid = (NN/16)*EI/4 blocks of 256. wave_gid = 4*blockIdx + wave -> (tile, eighth).
__launch_bounds__(256, 1)
__global__ void screen_bf16(const ushort_t* __restrict__ xb, const float* __restrict__ sq,
                            int* __restrict__ cand) {
  const int tid  = threadIdx.x;
  const int lane = tid & 63;
  const int wave = tid >> 6;
  const int g4   = lane >> 4;
  const int l16  = lane & 15;
  const int wgid = blockIdx.x * 4 + wave;
  const int tile = wgid >> 3;
  const int eighth = wgid & 7;
  const int i0   = tile * 16;

  bf16x8 af[8];
  {
    const ushort_t* ap = xb + (size_t)(i0 + l16) * CC + 8 * g4;
#pragma unroll
    for (int ks = 0; ks < 8; ++ks) af[ks] = *(const bf16x8*)(ap + ks * 32);
  }
  float sqi[4];
#pragma unroll
  for (int r = 0; r < 4; ++r) sqi[r] = sq[i0 + 4 * g4 + r];

  float ld[4][LLEN]; int lj[4][LLEN];
#pragma unroll
  for (int r = 0; r < 4; ++r)
#pragma unroll
    for (int s = 0; s < LLEN; ++s) { ld[r][s] = INFINITY; lj[r][s] = 0x7fffffff; }

  const int jbeg = eighth * (NN / EI);
#pragma unroll 1
  for (int t = 0; t < (NN / EI) / 64; ++t) {
    const int j0 = jbeg + t * 64;
#pragma unroll
    for (int jt = 0; jt < 4; ++jt) {
      f32x4 acc = {0.f, 0.f, 0.f, 0.f};
      const ushort_t* bp = xb + (size_t)(j0 + jt * 16 + l16) * CC + 8 * g4;
#pragma unroll
      for (int ks = 0; ks < 8; ++ks) {
        const bf16x8 bv = *(const bf16x8*)(bp + ks * 32);
        acc = __builtin_amdgcn_mfma_f32_16x16x32_bf16(af[ks], bv, acc, 0, 0, 0);
      }
      const int jc = j0 + jt * 16 + l16;
      const float sqj = sq[jc];
#pragma unroll
      for (int r = 0; r < 4; ++r) {
        const float dv = (sqi[r] + sqj) - 2.f * acc[r];
        const bool self = (jc == i0 + 4 * g4 + r);
        if (!self && (dv < ld[r][LLEN - 1] ||
                      (dv == ld[r][LLEN - 1] && jc < lj[r][LLEN - 1]))) {
          ld[r][LLEN - 1] = dv; lj[r][LLEN - 1] = jc;
#pragma unroll
          for (int s = LLEN - 1; s > 0; --s) {
            const bool sw = (ld[r][s] < ld[r][s - 1]) ||
                            (ld[r][s] == ld[r][s - 1] && lj[r][s] < lj[r][s - 1]);
            const float tv = ld[r][s - 1]; const int jv = lj[r][s - 1];
            ld[r][s - 1] = sw ? ld[r][s] : ld[r][s - 1];
            lj[r][s - 1] = sw ? lj[r][s] : lj[r][s - 1];
            ld[r][s] = sw ? tv : ld[r][s];
            lj[r][s] = sw ? jv : lj[r][s];
          }
        }
      }
    }
  }

  // extraction: per row, NCH rounds of 16-lane-group min (lex (d,j))
#pragma unroll
  for (int r = 0; r < 4; ++r) {
    const int rr = 4 * g4 + r;
#pragma unroll 1
    for (int s = 0; s < NCH; ++s) {
      float hd = ld[r][0]; int hj = lj[r][0];
#pragma unroll
      for (int dlt = 1; dlt < 16; dlt <<= 1) {
        const float od = __shfl_xor(hd, dlt);
        const int oj = __shfl_xor(hj, dlt);
        if (od < hd || (od == hd && oj < hj)) { hd = od; hj = oj; }
      }
      if (ld[r][0] == hd && lj[r][0] == hj) {
#pragma unroll
        for (int s2 = 0; s2 < LLEN - 1; ++s2) {
          ld[r][s2] = ld[r][s2 + 1]; lj[r][s2] = lj[r][s2 + 1];
        }
        ld[r][LLEN - 1] = INFINITY; lj[r][LLEN - 1] = 0x7fffffff;
      }
      if (l16 == 0) cand[(size_t)(i0 + rr) * NC + eighth * NCH + s] = hj;
    }
  }
}

// ---------------- refine: wave-coop coalesced fp32-gather, fp64 math ----------------
__launch_bounds__(256, 1)
__global__ void refine128c(const float* __restrict__ x32, const int* __restrict__ cand,
                           int* __restrict__ kj, double* __restrict__ kd,
                           double* __restrict__ gapd) {
  __shared__ double rd[NC];
  __shared__ int    rj[NC];
  __shared__ float  xi[CC];
  const int row = blockIdx.x;
  const int tid = threadIdx.x;
  const int wave = tid >> 6;
  const int lane = tid & 63;
  xi[tid] = x32[(size_t)row * CC + tid];
  __syncthreads();
#pragma unroll 1
  for (int c = wave; c < NC; c += 4) {
    const int j = cand[(size_t)row * NC + c];
    const f32x4 xjv = *(const f32x4*)(x32 + (size_t)j * CC + 4 * lane);
    const f32x4 xiv = *(const f32x4*)(&xi[4 * lane]);
    double p = 0.0;
    const double t0 = (double)xiv[0] - (double)xjv[0]; p = fma(t0, t0, p);
    const double t1 = (double)xiv[1] - (double)xjv[1]; p = fma(t1, t1, p);
    const double t2 = (double)xiv[2] - (double)xjv[2]; p = fma(t2, t2, p);
    const double t3 = (double)xiv[3] - (double)xjv[3]; p = fma(t3, t3, p);
#pragma unroll
    for (int d = 1; d < 64; d <<= 1) p += shfl_xor_d(p, d);
    if (lane == 0) { rd[c] = p; rj[c] = j; }
  }
  __syncthreads();
  if (tid < 64) {
    volatile double* vd = rd;
    volatile int*    vj = rj;
    double d16 = 0.0, d17 = 0.0;
    for (int s = 0; s < KE; ++s) {
      double bv = 1e300; int bj = 0x7fffffff; int bp = -1;
      for (int e = tid; e < NC; e += 64) {
        const double v = vd[e];
        const int jv = vj[e];
        if (v < bv || (v == bv && jv < bj)) { bv = v; bj = jv; bp = e; }
      }
#pragma unroll
      for (int dlt = 1; dlt < 64; dlt <<= 1) {
        const double ov = shfl_xor_d(bv, dlt);
        const int oj = __shfl_xor(bj, dlt);
        const int op = __shfl_xor(bp, dlt);
        if (ov < bv || (ov == bv && oj < bj)) { bv = ov; bj = oj; bp = op; }
      }
      if (tid == 0) {
        kj[(size_t)row * KE + s] = bj;
        kd[(size_t)row * KE + s] = bv;
        vd[bp] = 1e300;
        vj[bp] = 0x7fffffff;
      }
      if (s == KK - 1) d16 = bv;
      if (s == KK)     d17 = bv;
    }
    if (tid == 0) gapd[row] = d17 - d16;
  }
}

// ---------------- dual-branch softmax+aggregate + gated blend (+aux epilogue) ----------------
__global__ void agg_blend(const double* __restrict__ xin, const double* __restrict__ h,
                          const int* __restrict__ knn, int ldk, const double* __restrict__ gapd,
                          const double* __restrict__ als, const double* __restrict__ ald,
                          const float* __restrict__ bias, double tau,
                          double* __restrict__ xd_out, ushort_t* __restrict__ xb_out,
                          float* __restrict__ sq_out, float* __restrict__ x32_out,
                          int do_aux) {
  const int i = blockIdx.x;
  const int tid = threadIdx.x;
  __shared__ int idx[K17 + 1];
  __shared__ double attA[K17 + 1];
  __shared__ double attB[K17 + 1];
  __shared__ float red[256];
  if (tid < K17) idx[tid] = knn[(size_t)i * ldk + tid];
  if (tid == K17) idx[K17] = i;
  __syncthreads();
  if (tid == 0) {
    double e[K17 + 1];
#pragma unroll
    for (int l = 0; l < K17 + 1; ++l) {
      const double t = als[idx[l]] + ald[i];
      e[l] = (t >= 0.0) ? t : 0.2 * t;
    }
    {  // branch A: {0..15} + self
      double mx = e[K17];
#pragma unroll
      for (int l = 0; l < KK; ++l) mx = fmax(mx, e[l]);
      double den = 0.0, p[K17 + 1];
#pragma unroll
      for (int l = 0; l < KK; ++l) { p[l] = exp(e[l] - mx); den += p[l]; }
      p[K17] = exp(e[K17] - mx); den += p[K17];
      const double inv = 1.0 / den;
#pragma unroll
      for (int l = 0; l < K17 + 1; ++l) attA[l] = 0.0;
#pragma unroll
      for (int l = 0; l < KK; ++l) attA[l] = p[l] * inv;
      attA[K17] = p[K17] * inv;
    }
    {  // branch B: {0..14, 16} + self
      double mx = e[K17];
#pragma unroll
      for (int l = 0; l < KK - 1; ++l) mx = fmax(mx, e[l]);
      mx = fmax(mx, e[KK]);
      double den = 0.0, p[K17 + 1];
#pragma unroll
      for (int l = 0; l < KK - 1; ++l) { p[l] = exp(e[l] - mx); den += p[l]; }
      p[KK] = exp(e[KK] - mx); den += p[KK];
      p[K17] = exp(e[K17] - mx); den += p[K17];
      const double inv = 1.0 / den;
#pragma unroll
      for (int l = 0; l < K17 + 1; ++l) attB[l] = 0.0;
#pragma unroll
      for (int l = 0; l < KK - 1; ++l) attB[l] = p[l] * inv;
      attB[KK] = p[KK] * inv;
      attB[K17] = p[K17] * inv;
    }
  }
  __syncthreads();
  double outA = 0.0, outB = 0.0;
#pragma unroll 1
  for (int l = 0; l < K17 + 1; ++l) {
    const double hv = h[(size_t)idx[l] * CC + tid];
    outA += attA[l] * hv;
    outB += attB[l] * hv;
  }
  const double xv = xin[(size_t)i * CC + tid];
  const double bb = (double)bias[tid];
  const double rA = xv + fmax(outA + bb, 0.0);
  const double rB = xv + fmax(outB + bb, 0.0);
  red[tid] = (float)fabs(rA - rB);
  __syncthreads();
  for (int s = 128; s > 0; s >>= 1) {
    if (tid < s) red[tid] = fmaxf(red[tid], red[tid + s]);
    __syncthreads();
  }
  const bool blend = (gapd[i] < tau) && (red[0] <= DGATE);
  const double res = blend ? 0.5 * (rA + rB) : rA;
  xd_out[(size_t)i * CC + tid] = res;
  if (do_aux) {
    const float x32 = (float)res;
    __hip_bfloat16 hb = __float2bfloat16(x32);
    xb_out[(size_t)i * CC + tid] = *(ushort_t*)&hb;
    x32_out[(size_t)i * CC + tid] = x32;
    __syncthreads();
    red[tid] = x32 * x32;
    __syncthreads();
    for (int s = 128; s > 0; s >>= 1) {
      if (tid < s) red[tid] += red[tid + s];
      __syncthreads();
    }
    if (tid == 0) sq_out[i] = red[0];
  }
}

// ---------------- pick NF smallest layer-1 gaps (< TAUF) ----------------
__global__ void select_forks(const double* __restrict__ gapd, int* __restrict__ forks) {
  const int lane = threadIdx.x;
  int ch0 = -2, ch1 = -2;
  for (int f = 0; f < NF; ++f) {
    double bv = TAUF; int bi = 0x7fffffff;
    for (int i = lane; i < NN; i += 64) {
      if (i == ch0 || i == ch1) continue;
      const double v = gapd[i];
      if (v < bv || (v == bv && i < bi)) { bv = v; bi = i; }
    }
#pragma unroll
    for (int d = 1; d < 64; d <<= 1) {
      const double ov = shfl_xor_d(bv, d);
      const int oi = __shfl_xor(bi, d);
      if (ov < bv || (ov == bv && oi < bi)) { bv = ov; bi = oi; }
    }
    const int win = (bi == 0x7fffffff) ? -1 : bi;
    if (lane == 0) forks[f] = win;
    if (f == 0) ch0 = win;
    if (f == 1) ch1 = win;
  }
}

// ---------------- branch-B layer-1 output row per fork ----------------
__global__ void fork_rowB(const double* __restrict__ xin, const double* __restrict__ h,
                          const int* __restrict__ knn, const double* __restrict__ als,
                          const double* __restrict__ ald, const float* __restrict__ bias,
                          const int* __restrict__ forks, double* __restrict__ rowB) {
  const int f = blockIdx.x;
  const int tid = threadIdx.x;
  const int i = forks[f];
  if (i < 0) { rowB[(size_t)f * CC + tid] = 0.0; return; }
  __shared__ int idx[K17 + 1];
  __shared__ double attB[K17 + 1];
  if (tid < K17) idx[tid] = knn[(size_t)i * KE + tid];
  if (tid == K17) idx[K17] = i;
  __syncthreads();
  if (tid == 0) {
    double e[K17 + 1];
#pragma unroll
    for (int l = 0; l < K17 + 1; ++l) {
      const double t = als[idx[l]] + ald[i];
      e[l] = (t >= 0.0) ? t : 0.2 * t;
    }
    double mx = e[K17];
#pragma unroll
    for (int l = 0; l < KK - 1; ++l) mx = fmax(mx, e[l]);
    mx = fmax(mx, e[KK]);
    double den = 0.0, p[K17 + 1];
#pragma unroll
    for (int l = 0; l < KK - 1; ++l) { p[l] = exp(e[l] - mx); den += p[l]; }
    p[KK] = exp(e[KK] - mx); den += p[KK];
    p[K17] = exp(e[K17] - mx); den += p[K17];
    const double inv = 1.0 / den;
#pragma unroll
    for (int l = 0; l < K17 + 1; ++l) attB[l] = 0.0;
#pragma unroll
    for (int l = 0; l < KK - 1; ++l) attB[l] = p[l] * inv;
    attB[KK] = p[KK] * inv;
    attB[K17] = p[K17] * inv;
  }
  __syncthreads();
  double outB = 0.0;
#pragma unroll 1
  for (int l = 0; l < K17 + 1; ++l)
    outB += attB[l] * h[(size_t)idx[l] * CC + tid];
  rowB[(size_t)f * CC + tid] =
      xin[(size_t)i * CC + tid] + fmax(outB + (double)bias[tid], 0.0);
}

// ---------------- f-folded: hm = rowB @ W2 + als_m/ald_m ----------------
__global__ void fork_hm_alpha(const double* __restrict__ rowB, const float* __restrict__ W2,
                              const float* __restrict__ a_s2, const float* __restrict__ a_d2,
                              const int* __restrict__ forks,
                              double* __restrict__ hm3, double* __restrict__ alsm3,
                              double* __restrict__ aldm3) {
  const int f = blockIdx.x;
  const int m = forks[f];
  if (m < 0) return;
  __shared__ double rb[CC];
  __shared__ double hs[CC];
  const int tid = threadIdx.x;
  rb[tid] = rowB[(size_t)f * CC + tid];
  __syncthreads();
  double acc = 0.0;
  const float* wp = W2 + tid;
  for (int k = 0; k < CC; ++k) {
    const double w = (double)wp[(size_t)k * CC];
    acc += rb[k] * w;
  }
  hm3[(size_t)f * CC + tid] = acc;
  hs[tid] = acc;
  __syncthreads();
  if (tid < 64) {
    const double* hp = hs + 4 * tid;
    double s = 0.0, t = 0.0;
#pragma unroll
    for (int q = 0; q < 4; ++q) {
      const double hv = hp[q];
      s += hv * (double)a_s2[4 * tid + q];
      t += hv * (double)a_d2[4 * tid + q];
    }
#pragma unroll
    for (int d = 1; d < 64; d <<= 1) {
      s += shfl_xor_d(s, d);
      t += shfl_xor_d(t, d);
    }
    if (tid == 0) { alsm3[f] = s; aldm3[f] = t; }
  }
}

// ---------------- f-folded: dmB3[f][i] = ||x1A_i - rowB_f||^2 ----------------
__global__ void fork_dm(const double* __restrict__ x1A, const double* __restrict__ rowB,
                        const int* __restrict__ forks, double* __restrict__ dmB3) {
  const int f = blockIdx.x / (NN / 256);
  const int ib = blockIdx.x % (NN / 256);
  const int m = forks[f];
  if (m < 0) return;
  __shared__ double rb[CC];
  const int tid = threadIdx.x;
  rb[tid] = rowB[(size_t)f * CC + tid];
  __syncthreads();
  const int i = ib * 256 + tid;
  const double* xi = x1A + (size_t)i * CC;
  double acc = 0.0;
#pragma unroll 4
  for (int k = 0; k < CC; ++k) {
    const double t = xi[k] - rb[k];
    acc = fma(t, t, acc);
  }
  dmB3[(size_t)f * NN + i] = acc;
}

// ---------------- f-folded: incremental top-17, affected rows only ----------------
__global__ void fork_update_knn(const int* __restrict__ kj, const double* __restrict__ kd,
                                const double* __restrict__ dmB3, const int* __restrict__ forks,
                                int* __restrict__ kbj3, double* __restrict__ gapdB3,
                                int* __restrict__ afflist, int* __restrict__ affcnt) {
  const int f = blockIdx.x / (NN / 4);
  const int rb = blockIdx.x % (NN / 4);
  const int m = forks[f];
  if (m < 0) return;
  const int row = rb * 4 + (threadIdx.x >> 6);
  const int lane = threadIdx.x & 63;
  if (row == m) return;
  double d = 1e300;
  int j = 0x7fffffff;
  if (lane < KE) { j = kj[(size_t)row * KE + lane]; d = kd[(size_t)row * KE + lane]; }
  const ull pres = __ballot(lane < KE && j == m);
  const double dm = dmB3[(size_t)f * NN + row];
  const double k17d = kd[(size_t)row * KE + K17 - 1];
  const int    k17j = kj[(size_t)row * KE + K17 - 1];
  const bool ins = (dm < k17d) || (dm == k17d && m < k17j);
  if (pres == 0ull && !ins) return;          // unaffected: fB == fA bit-identical
  if (lane < KE && j == m) d = dm;
  if (lane == KE && pres == 0ull) { j = m; d = dm; }
  double d16 = 0.0, d17 = 0.0;
#pragma unroll 1
  for (int s = 0; s < K17; ++s) {
    double v = d; int e = j;
#pragma unroll
    for (int dlt = 1; dlt < 64; dlt <<= 1) {
      const double ov = shfl_xor_d(v, dlt);
      const int oe = __shfl_xor(e, dlt);
      if (ov < v || (ov == v && oe < e)) { v = ov; e = oe; }
    }
    if (j == e) d = 1e300;
    if (lane == 0) kbj3[((size_t)f * NN + row) * K17 + s] = e;
    if (s == KK - 1) d16 = v;
    if (s == KK)     d17 = v;
  }
  if (lane == 0) {
    gapdB3[(size_t)f * NN + row] = d17 - d16;
    const int slot = atomicAdd(&affcnt[f], 1);
    if (slot < CAP) afflist[(size_t)f * CAP + slot] = row;
  }
}

// ---------------- f-folded: row m's own top-17 over dmB ----------------
__launch_bounds__(256, 1)
__global__ void fork_row_m_knn(const double* __restrict__ dmB3, const int* __restrict__ forks,
                               int* __restrict__ kbj3, double* __restrict__ gapdB3,
                               int* __restrict__ afflist, int* __restrict__ affcnt) {
  const int f = blockIdx.x;
  const int m = forks[f];
  if (m < 0) return;
  __shared__ double md[256 * 18];
  __shared__ int    mj[256 * 18];
  const int tid = threadIdx.x;
  double td[18]; int tj[18];
#pragma unroll
  for (int s = 0; s < 18; ++s) { td[s] = 1e300; tj[s] = 0x7fffffff; }
  for (int j = tid; j < NN; j += 256) {
    if (j == m) continue;
    const double d = dmB3[(size_t)f * NN + j];
    if (d < td[17] || (d == td[17] && j < tj[17])) {
      td[17] = d; tj[17] = j;
#pragma unroll
      for (int s = 17; s > 0; --s) {
        const bool sw = (td[s] < td[s - 1]) ||
                        (td[s] == td[s - 1] && tj[s] < tj[s - 1]);
        const double tv = td[s - 1]; const int jv = tj[s - 1];
        td[s - 1] = sw ? td[s] : td[s - 1];
        tj[s - 1] = sw ? tj[s] : tj[s - 1];
        td[s] = sw ? tv : td[s];
        tj[s] = sw ? jv : tj[s];
      }
    }
  }
#pragma unroll
  for (int s = 0; s < 18; ++s) { md[tid * 18 + s] = td[s]; mj[tid * 18 + s] = tj[s]; }
  __syncthreads();
  if (tid < 64) {
    volatile double* vmd = md;
    volatile int*    vmj = mj;
    double d16 = 0.0, d17 = 0.0;
    for (int r = 0; r < K17; ++r) {
      double bv = 1e300; int bj = 0x7fffffff; int bp = -1;
      for (int e = tid; e < 256 * 18; e += 64) {
        const double v = vmd[e];
        const int jv = vmj[e];
        if (v < bv || (v == bv && jv < bj)) { bv = v; bj = jv; bp = e; }
      }
#pragma unroll
      for (int dlt = 1; dlt < 64; dlt <<= 1) {
        const double ov = shfl_xor_d(bv, dlt);
        const int oj = __shfl_xor(bj, dlt);
        const int op = __shfl_xor(bp, dlt);
        if (ov < bv || (ov == bv && oj < bj)) { bv = ov; bj = oj; bp = op; }
      }
      if (tid == 0) {
        kbj3[((size_t)f * NN + m) * K17 + r] = bj;
        vmd[bp] = 1e300;
        vmj[bp] = 0x7fffffff;
      }
      if (r == KK - 1) d16 = bv;
      if (r == KK)     d17 = bv;
    }
    if (tid == 0) {
      gapdB3[(size_t)f * NN + m] = d17 - d16;
      const int slot = atomicAdd(&affcnt[f], 1);
      if (slot < CAP) afflist[(size_t)f * CAP + slot] = m;
    }
  }
}

// ---------------- f-folded: agg over affected rows -> compact fnBc + maxd ----------------
__global__ void fork_agg_aff(const double* __restrict__ x1A, const double* __restrict__ h,
                             const int* __restrict__ kbj3, const double* __restrict__ gapdB3,
                             const double* __restrict__ als, const double* __restrict__ ald,
                             const double* __restrict__ alsm3, const double* __restrict__ aldm3,
                             const double* __restrict__ hm3, const double* __restrict__ rowB,
                             const float* __restrict__ bias, const int* __restrict__ forks,
                             const int* __restrict__ afflist, const int* __restrict__ affcnt,
                             const double* __restrict__ fnA, double* __restrict__ fnBc,
                             unsigned* __restrict__ maxd) {
  const int f = blockIdx.x >> 7;          // 128 blocks per fork
  const int qb = blockIdx.x & 127;
  const int m = forks[f];
  if (m < 0) return;
  const int cnt = min(affcnt[f], CAP);
  const int tid = threadIdx.x;
  __shared__ int idx[K17 + 1];
  __shared__ double attA[K17 + 1];
  __shared__ double attB[K17 + 1];
  __shared__ float red[256];
#pragma unroll 1
  for (int q = qb; q < cnt; q += 128) {
    const int i = afflist[(size_t)f * CAP + q];
    if (tid < K17) idx[tid] = kbj3[((size_t)f * NN + i) * K17 + tid];
    if (tid == K17) idx[K17] = i;
    __syncthreads();
    if (tid == 0) {
      const double aldi = (i == m) ? aldm3[f] : ald[i];
      double e[K17 + 1];
#pragma unroll
      for (int l = 0; l < K17 + 1; ++l) {
        const int ix = idx[l];
        const double a = (ix == m) ? alsm3[f] : als[ix];
        const double t = a + aldi;
        e[l] = (t >= 0.0) ? t : 0.2 * t;
      }
      {
        double mx = e[K17];
#pragma unroll
        for (int l = 0; l < KK; ++l) mx = fmax(mx, e[l]);
        double den = 0.0, p[K17 + 1];
#pragma unroll
        for (int l = 0; l < KK; ++l) { p[l] = exp(e[l] - mx); den += p[l]; }
        p[K17] = exp(e[K17] - mx); den += p[K17];
        const double inv = 1.0 / den;
#pragma unroll
        for (int l = 0; l < K17 + 1; ++l) attA[l] = 0.0;
#pragma unroll
        for (int l = 0; l < KK; ++l) attA[l] = p[l] * inv;
        attA[K17] = p[K17] * inv;
      }
      {
        double mx = e[K17];
#pragma unroll
        for (int l = 0; l < KK - 1; ++l) mx = fmax(mx, e[l]);
        mx = fmax(mx, e[KK]);
        double den = 0.0, p[K17 + 1];
#pragma unroll
        for (int l = 0; l < KK - 1; ++l) { p[l] = exp(e[l] - mx); den += p[l]; }
        p[KK] = exp(e[KK] - mx); den += p[KK];
        p[K17] = exp(e[K17] - mx); den += p[K17];
        const double inv = 1.0 / den;
#pragma unroll
        for (int l = 0; l < K17 + 1; ++l) attB[l] = 0.0;
#pragma unroll
        for (int l = 0; l < KK - 1; ++l) attB[l] = p[l] * inv;
        attB[KK] = p[KK] * inv;
        attB[K17] = p[K17] * inv;
      }
    }
    __syncthreads();
    double outA = 0.0, outB = 0.0;
#pragma unroll 1
    for (int l = 0; l < K17 + 1; ++l) {
      const int ix = idx[l];
      const double hv = (ix == m) ? hm3[(size_t)f * CC + tid] : h[(size_t)ix * CC + tid];
      outA += attA[l] * hv;
      outB += attB[l] * hv;
    }
    const double xv = (i == m) ? rowB[(size_t)f * CC + tid] : x1A[(size_t)i * CC + tid];
    const double bb = (double)bias[tid];
    const double rA = xv + fmax(outA + bb, 0.0);
    const double rB = xv + fmax(outB + bb, 0.0);
    red[tid] = (float)fabs(rA - rB);
    __syncthreads();
    for (int s = 128; s > 0; s >>= 1) {
      if (tid < s) red[tid] = fmaxf(red[tid], red[tid + s]);
      __syncthreads();
    }
    const bool blend = (gapdB3[(size_t)f * NN + i] < TAU_L2) && (red[0] <= DGATE);
    const double res = blend ? 0.5 * (rA + rB) : rA;
    fnBc[((size_t)f * CAP + q) * CC + tid] = res;
    red[tid] = (float)fabs(res - fnA[(size_t)i * CC + tid]);
    __syncthreads();
    for (int s = 128; s > 0; s >>= 1) {
      if (tid < s) red[tid] = fmaxf(red[tid], red[tid + s]);
      __syncthreads();
    }
    if (tid == 0) atomicMax(&maxd[f], __float_as_uint(red[0]));
    __syncthreads();
  }
}

// ---------------- gated corr accumulate (sequential per fork: no races) ----------------
__global__ void corr_aff(const double* __restrict__ fnA, const double* __restrict__ fnBc,
                         double* __restrict__ corr, const unsigned* __restrict__ maxd,
                         const int* __restrict__ forks, int f,
                         const int* __restrict__ afflist, const int* __restrict__ affcnt) {
  if (forks[f] < 0) return;
  if (__uint_as_float(maxd[f]) > DGATE) return;
  const int cnt = min(affcnt[f], CAP);
  const int tid = threadIdx.x;
#pragma unroll 1
  for (int q = blockIdx.x; q < cnt; q += 128) {
    const int i = afflist[(size_t)f * CAP + q];
    corr[(size_t)i * CC + tid] +=
        0.5 * (fnBc[((size_t)f * CAP + q) * CC + tid] - fnA[(size_t)i * CC + tid]);
  }
}

// ---------------- init corr + maxd + affcnt ----------------
__global__ void zero_init(double* __restrict__ corr, unsigned* __restrict__ maxd,
                          int* __restrict__ affcnt) {
  const size_t e = (size_t)blockIdx.x * 256 + threadIdx.x;
  corr[e] = 0.0;
  if (blockIdx.x == 0 && threadIdx.x < NF) {
    maxd[threadIdx.x] = 0u;
    affcnt[threadIdx.x] = 0;
  }
}

// ---------------- out = fA + corr ----------------
__global__ void final_write(const double* __restrict__ fA, const double* __restrict__ corr,
                            float* __restrict__ out) {
  const size_t e = (size_t)blockIdx.x * 256 + threadIdx.x;
  out[e] = (float)(fA[e] + corr[e]);
}

extern "C" void kernel_launch(void* const* d_in, const int* in_sizes, int n_in,
                              void* d_out, int out_size, void* d_ws, size_t ws_size,
                              hipStream_t stream) {
  const float* x0  = (const float*)d_in[0];
  const float* W   = (const float*)d_in[1];
  const float* a_s = (const float*)d_in[2];
  const float* a_d = (const float*)d_in[3];
  const float* b   = (const float*)d_in[4];
  float* out = (float*)d_out;

  char* ws = (char*)d_ws;
  double* xd0   = (double*)ws;  ws += (size_t)NN * CC * 8;   // 16 MB
  double* x1A   = (double*)ws;  ws += (size_t)NN * CC * 8;   // 16 MB
  double* h     = (double*)ws;  ws += (size_t)NN * CC * 8;   // 16 MB
  double* fnA   = (double*)ws;  ws += (size_t)NN * CC * 8;   // 16 MB
  double* corr  = (double*)ws;  ws += (size_t)NN * CC * 8;   // 16 MB
  double* fnBc  = (double*)ws;  ws += (size_t)NF * CAP * CC * 8;   // 12.6 MB
  float* x32A   = (float*)ws;   ws += (size_t)NN * CC * 4;   // 8 MB
  ushort_t* xb0 = (ushort_t*)ws; ws += (size_t)NN * CC * 2;  // 4 MB
  ushort_t* xbA = (ushort_t*)ws; ws += (size_t)NN * CC * 2;  // 4 MB
  float* sq0    = (float*)ws;   ws += (size_t)NN * 4;
  float* sqA    = (float*)ws;   ws += (size_t)NN * 4;
  double* als   = (double*)ws;  ws += (size_t)NN * 8;
  double* ald   = (double*)ws;  ws += (size_t)NN * 8;
  double* gapd  = (double*)ws;  ws += (size_t)NN * 8;
  double* gapdB3= (double*)ws;  ws += (size_t)NF * NN * 8;
  double* dmB3  = (double*)ws;  ws += (size_t)NF * NN * 8;
  int*   cand   = (int*)ws;     ws += (size_t)NN * NC * 4;   // 4 MB
  int*   kj     = (int*)ws;     ws += (size_t)NN * KE * 4;
  double* kd    = (double*)ws;  ws += (size_t)NN * KE * 8;
  int*   kbj3   = (int*)ws;     ws += (size_t)NF * NN * K17 * 4;
  int*   afflist= (int*)ws;     ws += (size_t)NF * CAP * 4;
  double* rowB  = (double*)ws;  ws += (size_t)NF * CC * 8;
  double* hm3   = (double*)ws;  ws += (size_t)NF * CC * 8;
  double* alsm3 = (double*)ws;  ws += 64 * 8;
  double* aldm3 = (double*)ws;  ws += 64 * 8;
  int*   forks  = (int*)ws;     ws += 64;
  unsigned* maxd = (unsigned*)ws; ws += 64;
  int*   affcnt = (int*)ws;     ws += 64;

  const int NE = NN * CC / 256;

  // ---- layer 1 ----
  xprep_kernel<<<NN, 256, 0, stream>>>(x0, xd0, xb0, sq0);
  hgemm64_kernel<<<NN / 16, 256, 0, stream>>>(xd0, W, h);
  alpha64_kernel<<<NN / 4, 256, 0, stream>>>(h, a_s, a_d, als, ald);
  screen_bf16<<<(NN / 16) * EI / 4, 256, 0, stream>>>(xb0, sq0, cand);
  refine128c<<<NN, 256, 0, stream>>>(x0, cand, kj, kd, gapd);   // fp32 src == exact
  agg_blend<<<NN, 256, 0, stream>>>(xd0, h, kj, KE, gapd, als, ald, b,
                                    0.0, x1A, xbA, sqA, x32A, 1);
  select_forks<<<1, 64, 0, stream>>>(gapd, forks);
  fork_rowB<<<NF, 256, 0, stream>>>(xd0, h, kj, als, ald, b, forks, rowB);
  zero_init<<<NE, 256, 0, stream>>>(corr, maxd, affcnt);

  // ---- layer 2, branch A ----
  hgemm64_kernel<<<NN / 16, 256, 0, stream>>>(x1A, W + (size_t)CC * CC, h);
  alpha64_kernel<<<NN / 4, 256, 0, stream>>>(h, a_s + CC, a_d + CC, als, ald);
  screen_bf16<<<(NN / 16) * EI / 4, 256, 0, stream>>>(xbA, sqA, cand);
  refine128c<<<NN, 256, 0, stream>>>(x32A, cand, kj, kd, gapd);
  agg_blend<<<NN, 256, 0, stream>>>(x1A, h, kj, KE, gapd, als, ald, b + CC,
                                    TAU_L2, fnA, (ushort_t*)0, (float*)0, (float*)0, 0);

  // ---- layer 2, f-folded incremental branch B (affected rows only) ----
  fork_hm_alpha<<<NF, 256, 0, stream>>>(rowB, W + (size_t)CC * CC, a_s + CC, a_d + CC,
                                        forks, hm3, alsm3, aldm3);
  fork_dm<<<(NN / 256) * NF, 256, 0, stream>>>(x1A, rowB, forks, dmB3);
  fork_update_knn<<<(NN / 4) * NF, 256, 0, stream>>>(kj, kd, dmB3, forks, kbj3, gapdB3,
                                                     afflist, affcnt);
  fork_row_m_knn<<<NF, 256, 0, stream>>>(dmB3, forks, kbj3, gapdB3, afflist, affcnt);
  fork_agg_aff<<<128 * NF, 256, 0, stream>>>(x1A, h, kbj3, gapdB3, als, ald, alsm3, aldm3,
                                             hm3, rowB, b + CC, forks, afflist, affcnt,
                                             fnA, fnBc, maxd);
  for (int f = 0; f < NF; ++f)
    corr_aff<<<128, 256, 0, stream>>>(fnA, fnBc, corr, maxd, forks, f, afflist, affcnt);

  final_write<<<NE, 256, 0, stream>>>(fnA, corr, out);
}